// Round 6
// baseline (912.900 us; speedup 1.0000x reference)
//
#include <hip/hip_runtime.h>
#include <math.h>

#define B_ 64
#define S_ 2048
#define H_ 1024
#define K_ 1024
#define M_ (B_*S_)   // 131072 rows of the big GEMM

using f32x4   = __attribute__((ext_vector_type(4))) float;
using bf16x8  = __attribute__((ext_vector_type(8))) __bf16;

__device__ __forceinline__ unsigned short f2b(float f) {
  unsigned int u = __float_as_uint(f);
  u += 0x7fffu + ((u >> 16) & 1u);   // RNE
  return (unsigned short)(u >> 16);
}

// tanh(x) = (e^2x - 1)/(e^2x + 1); clamp so t stays finite (tanh saturated anyway)
__device__ __forceinline__ float fast_tanh(float x) {
  float xc = fminf(fmaxf(x, -15.f), 15.f);
  float t = __expf(2.f * xc);
  return (t - 1.f) * __builtin_amdgcn_rcpf(t + 1.f);
}

typedef __attribute__((address_space(1))) void gvoid_t;
typedef __attribute__((address_space(3))) void lvoid_t;

__device__ __forceinline__ void async16(const void* g, void* l) {
  __builtin_amdgcn_global_load_lds((gvoid_t*)g, (lvoid_t*)l, 16, 0, 0);
}

// XOR-swizzled LDS element offset for (row r, 16B-slot s) in a [128][64] bf16 tile.
// 8 slots/row; phys_slot = s ^ (r&7): each 8-row stripe covers all 32 banks
// exactly twice per 16-lane column read (2-way = free) and per wave write.
__device__ __forceinline__ int swz64(int r, int s) {
  return r * 64 + ((s ^ (r & 7)) << 3);
}

// ---------------------------------------------------------------- mask dtype
// flag: 0 = int32 {0,1}, 1 = bytes (bool), 2 = float32 {0,1.0}
__global__ void detect_mask(const unsigned int* __restrict__ m, int* __restrict__ flag) {
  __shared__ int red[256];
  int t = threadIdx.x;
  int f = 0;
  for (int i = 0; i < 32; ++i) {
    unsigned int w = m[t * 32 + i];
    if (w > 1u) f |= 1;
    if (w != 0u && w != 0x3f800000u) f |= 2;
  }
  red[t] = f;
  __syncthreads();
  for (int o = 128; o > 0; o >>= 1) { if (t < o) red[t] |= red[t + o]; __syncthreads(); }
  if (t == 0) {
    int g = red[0];
    *flag = ((g & 1) == 0) ? 0 : (((g & 2) == 0) ? 2 : 1);
  }
}

// ---------------------------------------------------------------- Wk -> bf16
__global__ void convert_wk(const float* __restrict__ src, unsigned short* __restrict__ dst) {
  int i = blockIdx.x * blockDim.x + threadIdx.x;
  float4 v = ((const float4*)src)[i];
  ushort4 o;
  o.x = f2b(v.x); o.y = f2b(v.y); o.z = f2b(v.z); o.w = f2b(v.w);
  *(ushort4*)(dst + (size_t)i * 4) = o;
}

// ---------------------------------------------------------------- qp = query @ Wq.T
__global__ void qp_kernel(const float* __restrict__ query, const float* __restrict__ Wq,
                          float* __restrict__ qp) {
  __shared__ float qs[1024];
  const int b = blockIdx.x, t = threadIdx.x;
  ((float4*)qs)[t] = ((const float4*)(query + b * 1024))[t];
  __syncthreads();
#pragma unroll
  for (int i = 0; i < 4; ++i) {
    int h = t + i * 256;
    const float4* wr = (const float4*)(Wq + h * 1024);
    float s = 0.f;
    for (int q4 = 0; q4 < 256; ++q4) {
      float4 w = wr[q4];
      float4 q = ((const float4*)qs)[q4];
      s += w.x * q.x + w.y * q.y + w.z * q.z + w.w * q.w;
    }
    qp[b * 1024 + h] = s;
  }
}

// ---------------------------------------------------------------- fused GEMM + energy
// R2 structure (proven 556us) with BK=64: 16 K-steps instead of 32 -> half the
// barrier/drain events, 2x MFMA per step (32 calls). Single-buffered 32KB LDS
// keeps ~4-5 blocks/CU; all register indexing compile-time static.
__global__ __launch_bounds__(256) void gemm_energy(
    const float* __restrict__ keys,          // [M_][1024] f32
    const __bf16* __restrict__ wk,           // [1024][1024] bf16 (B^T layout)
    const float* __restrict__ qp,            // [64][1024]
    const float* __restrict__ v,             // [1024]
    float* __restrict__ energy) {            // [M_]
  __shared__ __align__(16) __bf16 As[128 * 64];
  __shared__ __align__(16) __bf16 Bs[128 * 64];

  const int tid  = threadIdx.x;
  const int w    = tid >> 6;
  const int lane = tid & 63;

  // XCD-bijective swizzle: all 8 n-tiles of one m-tile consecutive on one XCD
  const int orig = blockIdx.x;                   // 0..8191
  const int wgid = (orig & 7) * 1024 + (orig >> 3);
  const int m0 = (wgid >> 3) * 128;
  const int n0 = (wgid & 7) * 128;

  const int wm = w >> 1, wn = w & 1;

  f32x4 acc[4][4] = {};

  // A staging: 128x64 tile = 1024 chunks of 8 f32; this thread owns 4
  int arow[4], aslot[4];
#pragma unroll
  for (int i = 0; i < 4; ++i) {
    int c = tid + i * 256;
    arow[i]  = c >> 3;     // 0..127
    aslot[i] = c & 7;      // 0..7
  }
  const float* Abase = keys + (size_t)m0 * K_;

  // B stage: linear LDS dest, pre-swizzled global source slot
  int brow[4], bsrc[4];
#pragma unroll
  for (int j = 0; j < 4; ++j) {
    int c2 = j * 256 + tid;
    brow[j] = c2 >> 3;
    bsrc[j] = ((c2 & 7) ^ (brow[j] & 7)) * 8;
  }

  // prologue: load A chunks for k-tile 0
  float4 preA[4][2];
#pragma unroll
  for (int i = 0; i < 4; ++i) {
    const float* p = Abase + arow[i] * K_ + aslot[i] * 8;
    preA[i][0] = *(const float4*)p;
    preA[i][1] = *(const float4*)(p + 4);
  }

  for (int kt = 0; kt < 16; ++kt) {
    const int k0 = kt * 64;
    // cvt staged A regs -> bf16 -> swizzled LDS
#pragma unroll
    for (int i = 0; i < 4; ++i) {
      bf16x8 u;
      u[0] = (__bf16)preA[i][0].x; u[1] = (__bf16)preA[i][0].y;
      u[2] = (__bf16)preA[i][0].z; u[3] = (__bf16)preA[i][0].w;
      u[4] = (__bf16)preA[i][1].x; u[5] = (__bf16)preA[i][1].y;
      u[6] = (__bf16)preA[i][1].z; u[7] = (__bf16)preA[i][1].w;
      *(bf16x8*)(&As[swz64(arow[i], aslot[i])]) = u;
    }
    // stage B tile (L2-resident): linear dest, source column pre-permuted
#pragma unroll
    for (int j = 0; j < 4; ++j)
      async16(wk + (size_t)(n0 + brow[j]) * K_ + k0 + bsrc[j],
              &Bs[(size_t)(j * 256 + w * 64) * 8]);
    __syncthreads();
    // prefetch next A k-tile into regs (overlaps the MFMA section below)
    if (kt + 1 < 16) {
#pragma unroll
      for (int i = 0; i < 4; ++i) {
        const float* p = Abase + arow[i] * K_ + (k0 + 64) + aslot[i] * 8;
        preA[i][0] = *(const float4*)p;
        preA[i][1] = *(const float4*)(p + 4);
      }
    }
    // 2 k-substeps of 32: fragments + MFMA
    const int g = lane >> 4;
#pragma unroll
    for (int ks = 0; ks < 2; ++ks) {
      const int slot = ks * 4 + g;
      bf16x8 af[4], bfr[4];
#pragma unroll
      for (int mi = 0; mi < 4; ++mi) {
        int r = wm * 64 + mi * 16 + (lane & 15);
        af[mi] = *(const bf16x8*)(&As[swz64(r, slot)]);
      }
#pragma unroll
      for (int ni = 0; ni < 4; ++ni) {
        int r = wn * 64 + ni * 16 + (lane & 15);
        bfr[ni] = *(const bf16x8*)(&Bs[swz64(r, slot)]);
      }
#pragma unroll
      for (int mi = 0; mi < 4; ++mi)
#pragma unroll
        for (int ni = 0; ni < 4; ++ni)
          acc[mi][ni] = __builtin_amdgcn_mfma_f32_16x16x32_bf16(af[mi], bfr[ni], acc[mi][ni], 0, 0, 0);
    }
    __syncthreads();
  }

  // epilogue: C/D layout col = lane&15, row = (lane>>4)*4 + reg
  const int bb = m0 >> 11;
  float qpv[4], vv[4];
#pragma unroll
  for (int ni = 0; ni < 4; ++ni) {
    int h = n0 + wn * 64 + ni * 16 + (lane & 15);
    qpv[ni] = qp[bb * H_ + h];
    vv[ni]  = v[h];
  }
#pragma unroll
  for (int mi = 0; mi < 4; ++mi) {
    float ps[4] = {0.f, 0.f, 0.f, 0.f};
#pragma unroll
    for (int ni = 0; ni < 4; ++ni)
#pragma unroll
      for (int rr = 0; rr < 4; ++rr)
        ps[rr] += fast_tanh(acc[mi][ni][rr] + qpv[ni]) * vv[ni];
#pragma unroll
    for (int off = 1; off < 16; off <<= 1)
#pragma unroll
      for (int rr = 0; rr < 4; ++rr)
        ps[rr] += __shfl_xor(ps[rr], off, 64);
    if ((lane & 15) == 0) {
      int rowbase = m0 + wm * 64 + mi * 16 + (lane >> 4) * 4;
#pragma unroll
      for (int rr = 0; rr < 4; ++rr)
        atomicAdd(&energy[rowbase + rr], ps[rr]);
    }
  }
}

// ---------------------------------------------------------------- masked softmax
__global__ void softmax_kernel(const float* __restrict__ energy, const void* __restrict__ mask,
                               const int* __restrict__ flag, float* __restrict__ attn) {
  __shared__ float red[256];
  const int b = blockIdx.x, t = threadIdx.x;
  const int fl = *flag;
  float e[8];
#pragma unroll
  for (int i = 0; i < 8; ++i) {
    int s = i * 256 + t;
    int idx = b * S_ + s;
    bool m;
    if (fl == 1)      m = ((const unsigned char*)mask)[idx] != 0;
    else if (fl == 2) m = ((const float*)mask)[idx] != 0.f;
    else              m = ((const int*)mask)[idx] != 0;
    e[i] = m ? -INFINITY : energy[idx];
  }
  float mx = e[0];
#pragma unroll
  for (int i = 1; i < 8; ++i) mx = fmaxf(mx, e[i]);
  red[t] = mx; __syncthreads();
  for (int o = 128; o > 0; o >>= 1) { if (t < o) red[t] = fmaxf(red[t], red[t + o]); __syncthreads(); }
  mx = red[0];
  __syncthreads();
  const bool any = (mx > -INFINITY);
  float p[8]; float sum = 0.f;
#pragma unroll
  for (int i = 0; i < 8; ++i) {
    p[i] = (any && e[i] > -INFINITY) ? __expf(e[i] - mx) : 0.f;
    sum += p[i];
  }
  red[t] = sum; __syncthreads();
  for (int o = 128; o > 0; o >>= 1) { if (t < o) red[t] += red[t + o]; __syncthreads(); }
  sum = red[0];
  const float inv = (sum > 0.f) ? 1.f / sum : 0.f;
#pragma unroll
  for (int i = 0; i < 8; ++i) attn[b * S_ + i * 256 + t] = p[i] * inv;
}

// ---------------------------------------------------------------- context = attn @ keys
__global__ void context_kernel(const float* __restrict__ attn, const float* __restrict__ keys,
                               float* __restrict__ ctx) {
  const int b = blockIdx.y;
  const int sc = blockIdx.x;          // 16 chunks of 128 s
  const int t = threadIdx.x;          // k = 4t..4t+3
  const float* kb = keys + ((size_t)b * S_ + sc * 128) * K_;
  const float* ab = attn + b * S_ + sc * 128;
  float4 acc = {0.f, 0.f, 0.f, 0.f};
  for (int s = 0; s < 128; ++s) {
    float a = ab[s];                   // block-uniform
    if (a != 0.f) {                    // skip padded positions entirely
      float4 kv = *(const float4*)(kb + (size_t)s * K_ + t * 4);
      acc.x += a * kv.x; acc.y += a * kv.y; acc.z += a * kv.z; acc.w += a * kv.w;
    }
  }
  float* cb = ctx + b * K_ + t * 4;
  atomicAdd(cb + 0, acc.x);
  atomicAdd(cb + 1, acc.y);
  atomicAdd(cb + 2, acc.z);
  atomicAdd(cb + 3, acc.w);
}

// ---------------------------------------------------------------- launch
extern "C" void kernel_launch(void* const* d_in, const int* in_sizes, int n_in,
                              void* d_out, int out_size, void* d_ws, size_t ws_size,
                              hipStream_t stream) {
  (void)in_sizes; (void)n_in; (void)out_size; (void)ws_size;
  const float* query = (const float*)d_in[0];
  const float* keys  = (const float*)d_in[1];
  const void*  mask  = d_in[2];
  const float* Wq    = (const float*)d_in[3];
  const float* Wk    = (const float*)d_in[4];
  const float* v     = (const float*)d_in[5];

  float* ctx  = (float*)d_out;             // [64][1024]
  float* attn = (float*)d_out + B_ * K_;   // [64][2048]

  char* ws = (char*)d_ws;
  float*          energy = (float*)ws;                              // 512 KiB
  float*          qp     = (float*)(ws + (512 << 10));              // 256 KiB
  unsigned short* wkb    = (unsigned short*)(ws + (768 << 10));     // 2 MiB
  int*            flag   = (int*)(ws + (768 << 10) + (2 << 20));

  hipMemsetAsync(energy, 0, (size_t)M_ * 4, stream);
  hipMemsetAsync(ctx, 0, (size_t)B_ * K_ * 4, stream);
  detect_mask<<<1, 256, 0, stream>>>((const unsigned int*)mask, flag);
  convert_wk<<<(H_ * K_ / 4) / 256, 256, 0, stream>>>(Wk, wkb);
  qp_kernel<<<B_, 256, 0, stream>>>(query, Wq, qp);
  gemm_energy<<<(M_ / 128) * (H_ / 128), 256, 0, stream>>>(keys, (const __bf16*)wkb, qp, v, energy);
  softmax_kernel<<<B_, 256, 0, stream>>>(energy, mask, flag, attn);
  context_kernel<<<dim3(S_ / 128, B_), 256, 0, stream>>>(attn, keys, ctx);
}

// Round 7
// 691.682 us; speedup vs baseline: 1.3198x; 1.3198x over previous
//
#include <hip/hip_runtime.h>
#include <math.h>

#define B_ 64
#define S_ 2048
#define H_ 1024
#define K_ 1024
#define M_ (B_*S_)   // 131072 rows of the big GEMM

using f32x4   = __attribute__((ext_vector_type(4))) float;
using bf16x8  = __attribute__((ext_vector_type(8))) __bf16;

__device__ __forceinline__ unsigned short f2b(float f) {
  unsigned int u = __float_as_uint(f);
  u += 0x7fffu + ((u >> 16) & 1u);   // RNE
  return (unsigned short)(u >> 16);
}

// tanh(x) = (e^2x - 1)/(e^2x + 1); clamp so t stays finite (tanh saturated anyway)
__device__ __forceinline__ float fast_tanh(float x) {
  float xc = fminf(fmaxf(x, -15.f), 15.f);
  float t = __expf(2.f * xc);
  return (t - 1.f) * __builtin_amdgcn_rcpf(t + 1.f);
}

typedef __attribute__((address_space(1))) void gvoid_t;
typedef __attribute__((address_space(3))) void lvoid_t;

__device__ __forceinline__ void async16(const void* g, void* l) {
  __builtin_amdgcn_global_load_lds((gvoid_t*)g, (lvoid_t*)l, 16, 0, 0);
}

// XOR-swizzled LDS element offset for (row r, 16B-slot sl) in a [128][32] bf16 tile
__device__ __forceinline__ int swz(int r, int sl) {
  return r * 32 + ((sl ^ ((r >> 1) & 3)) << 3);
}

// ---------------------------------------------------------------- mask dtype
// flag: 0 = int32 {0,1}, 1 = bytes (bool), 2 = float32 {0,1.0}
__global__ void detect_mask(const unsigned int* __restrict__ m, int* __restrict__ flag) {
  __shared__ int red[256];
  int t = threadIdx.x;
  int f = 0;
  for (int i = 0; i < 32; ++i) {
    unsigned int w = m[t * 32 + i];
    if (w > 1u) f |= 1;
    if (w != 0u && w != 0x3f800000u) f |= 2;
  }
  red[t] = f;
  __syncthreads();
  for (int o = 128; o > 0; o >>= 1) { if (t < o) red[t] |= red[t + o]; __syncthreads(); }
  if (t == 0) {
    int g = red[0];
    *flag = ((g & 1) == 0) ? 0 : (((g & 2) == 0) ? 2 : 1);
  }
}

// ---------------------------------------------------------------- Wk -> bf16
__global__ void convert_wk(const float* __restrict__ src, unsigned short* __restrict__ dst) {
  int i = blockIdx.x * blockDim.x + threadIdx.x;
  float4 v = ((const float4*)src)[i];
  ushort4 o;
  o.x = f2b(v.x); o.y = f2b(v.y); o.z = f2b(v.z); o.w = f2b(v.w);
  *(ushort4*)(dst + (size_t)i * 4) = o;
}

// ---------------------------------------------------------------- keys -> bf16 (stream)
__global__ void convert_keys(const float* __restrict__ src, __bf16* __restrict__ dst,
                             long n8) {
  long i = (long)blockIdx.x * blockDim.x + threadIdx.x;
  const long stride = (long)gridDim.x * blockDim.x;
  for (; i < n8; i += stride) {
    const float4* p = (const float4*)(src + i * 8);
    float4 a = p[0], b = p[1];
    bf16x8 u;
    u[0] = (__bf16)a.x; u[1] = (__bf16)a.y; u[2] = (__bf16)a.z; u[3] = (__bf16)a.w;
    u[4] = (__bf16)b.x; u[5] = (__bf16)b.y; u[6] = (__bf16)b.z; u[7] = (__bf16)b.w;
    *(bf16x8*)(dst + i * 8) = u;
  }
}

// ---------------------------------------------------------------- qp = query @ Wq.T
__global__ void qp_kernel(const float* __restrict__ query, const float* __restrict__ Wq,
                          float* __restrict__ qp) {
  __shared__ float qs[1024];
  const int b = blockIdx.x, t = threadIdx.x;
  ((float4*)qs)[t] = ((const float4*)(query + b * 1024))[t];
  __syncthreads();
#pragma unroll
  for (int i = 0; i < 4; ++i) {
    int h = t + i * 256;
    const float4* wr = (const float4*)(Wq + h * 1024);
    float s = 0.f;
    for (int q4 = 0; q4 < 256; ++q4) {
      float4 w = wr[q4];
      float4 q = ((const float4*)qs)[q4];
      s += w.x * q.x + w.y * q.y + w.z * q.z + w.w * q.w;
    }
    qp[b * 1024 + h] = s;
  }
}

// ---------------------------------------------------------------- shared epilogue
__device__ __forceinline__ void energy_epilogue(
    f32x4 (&acc)[4][4], const float* qp, const float* v, float* energy,
    int m0, int n0, int wm, int wn, int lane) {
  const int bb = m0 >> 11;
  float qpv[4], vv[4];
#pragma unroll
  for (int ni = 0; ni < 4; ++ni) {
    int h = n0 + wn * 64 + ni * 16 + (lane & 15);
    qpv[ni] = qp[bb * H_ + h];
    vv[ni]  = v[h];
  }
#pragma unroll
  for (int mi = 0; mi < 4; ++mi) {
    float ps[4] = {0.f, 0.f, 0.f, 0.f};
#pragma unroll
    for (int ni = 0; ni < 4; ++ni)
#pragma unroll
      for (int rr = 0; rr < 4; ++rr)
        ps[rr] += fast_tanh(acc[mi][ni][rr] + qpv[ni]) * vv[ni];
#pragma unroll
    for (int off = 1; off < 16; off <<= 1)
#pragma unroll
      for (int rr = 0; rr < 4; ++rr)
        ps[rr] += __shfl_xor(ps[rr], off, 64);
    if ((lane & 15) == 0) {
      int rowbase = m0 + wm * 64 + mi * 16 + (lane >> 4) * 4;
#pragma unroll
      for (int rr = 0; rr < 4; ++rr)
        atomicAdd(&energy[rowbase + rr], ps[rr]);
    }
  }
}

// ---------------------------------------------------------------- GEMM+energy, bf16 keys
// m97 structure: both operands via global_load_lds (zero staging VGPRs, no cvt),
// 2 barriers/step, both-sides swizzle (pre-swizzled global source column).
__global__ __launch_bounds__(256, 4) void gemm_energy_b16(
    const __bf16* __restrict__ kb,           // [M_][1024] bf16 keys
    const __bf16* __restrict__ wk,           // [1024][1024] bf16 Wk
    const float* __restrict__ qp,
    const float* __restrict__ v,
    float* __restrict__ energy) {
  __shared__ __align__(16) __bf16 As[128 * 32];
  __shared__ __align__(16) __bf16 Bs[128 * 32];

  const int tid  = threadIdx.x;
  const int w    = tid >> 6;
  const int lane = tid & 63;

  const int orig = blockIdx.x;                   // 0..8191
  const int wgid = (orig & 7) * 1024 + (orig >> 3);
  const int m0 = (wgid >> 3) * 128;
  const int n0 = (wgid & 7) * 128;

  const int wm = w >> 1, wn = w & 1;

  f32x4 acc[4][4] = {};

  // staging geometry: 512 chunks of 8 bf16 per 128x32 tile; this thread owns 2
  int srow[2], soff[2], ldst[2];
#pragma unroll
  for (int j = 0; j < 2; ++j) {
    int c = tid + j * 256;
    srow[j] = c >> 2;
    soff[j] = (((c & 3) ^ ((srow[j] >> 1) & 3)) << 3);   // pre-swizzled source slot
    ldst[j] = (j * 256 + w * 64) * 8;                     // linear wave-uniform dest
  }
  const __bf16* Ab = kb + (size_t)m0 * K_;
  const __bf16* Bb = wk + (size_t)n0 * K_;

  for (int kt = 0; kt < 32; ++kt) {
    const int k0 = kt * 32;
#pragma unroll
    for (int j = 0; j < 2; ++j)
      async16(Ab + (size_t)srow[j] * K_ + k0 + soff[j], &As[ldst[j]]);
#pragma unroll
    for (int j = 0; j < 2; ++j)
      async16(Bb + (size_t)srow[j] * K_ + k0 + soff[j], &Bs[ldst[j]]);
    __syncthreads();
    const int g = lane >> 4;
    bf16x8 af[4], bfr[4];
#pragma unroll
    for (int mi = 0; mi < 4; ++mi) {
      int r = wm * 64 + mi * 16 + (lane & 15);
      af[mi] = *(const bf16x8*)(&As[swz(r, g)]);
    }
#pragma unroll
    for (int ni = 0; ni < 4; ++ni) {
      int r = wn * 64 + ni * 16 + (lane & 15);
      bfr[ni] = *(const bf16x8*)(&Bs[swz(r, g)]);
    }
#pragma unroll
    for (int mi = 0; mi < 4; ++mi)
#pragma unroll
      for (int ni = 0; ni < 4; ++ni)
        acc[mi][ni] = __builtin_amdgcn_mfma_f32_16x16x32_bf16(af[mi], bfr[ni], acc[mi][ni], 0, 0, 0);
    __syncthreads();
  }

  energy_epilogue(acc, qp, v, energy, m0, n0, wm, wn, lane);
}

// ---------------------------------------------------------------- fallback GEMM (R2, f32 keys)
__global__ __launch_bounds__(256) void gemm_energy(
    const float* __restrict__ keys,          // [M_][1024] f32
    const __bf16* __restrict__ wk,           // [1024][1024] bf16
    const float* __restrict__ qp,
    const float* __restrict__ v,
    float* __restrict__ energy) {
  __shared__ __align__(16) __bf16 As[128 * 32];
  __shared__ __align__(16) __bf16 Bs[128 * 32];

  const int tid  = threadIdx.x;
  const int w    = tid >> 6;
  const int lane = tid & 63;

  const int orig = blockIdx.x;
  const int wgid = (orig & 7) * 1024 + (orig >> 3);
  const int m0 = (wgid >> 3) * 128;
  const int n0 = (wgid & 7) * 128;

  const int wm = w >> 1, wn = w & 1;

  f32x4 acc[4][4] = {};

  int arow[2], aslot[2];
#pragma unroll
  for (int i = 0; i < 2; ++i) {
    int c = tid + i * 256;
    arow[i]  = c >> 2;
    aslot[i] = c & 3;
  }
  const float* Abase = keys + (size_t)m0 * K_;

  int brow[2], bs_src[2], bs_dst[2];
#pragma unroll
  for (int j = 0; j < 2; ++j) {
    int flat = w * 1024 + j * 512 + lane * 8;
    brow[j]   = flat >> 5;
    bs_src[j] = (((flat >> 3) & 3) ^ ((brow[j] >> 1) & 3)) * 8;
    bs_dst[j] = w * 1024 + j * 512;
  }

  float4 pre[2][2];
#pragma unroll
  for (int i = 0; i < 2; ++i) {
    const float* p = Abase + arow[i] * K_ + aslot[i] * 8;
    pre[i][0] = *(const float4*)p;
    pre[i][1] = *(const float4*)(p + 4);
  }

  for (int kt = 0; kt < 32; ++kt) {
    const int k0 = kt * 32;
#pragma unroll
    for (int i = 0; i < 2; ++i) {
      bf16x8 u;
      u[0] = (__bf16)pre[i][0].x; u[1] = (__bf16)pre[i][0].y;
      u[2] = (__bf16)pre[i][0].z; u[3] = (__bf16)pre[i][0].w;
      u[4] = (__bf16)pre[i][1].x; u[5] = (__bf16)pre[i][1].y;
      u[6] = (__bf16)pre[i][1].z; u[7] = (__bf16)pre[i][1].w;
      *(bf16x8*)(&As[swz(arow[i], aslot[i])]) = u;
    }
#pragma unroll
    for (int j = 0; j < 2; ++j)
      async16(wk + (size_t)(n0 + brow[j]) * K_ + k0 + bs_src[j], &Bs[bs_dst[j]]);
    __syncthreads();
    if (kt + 1 < 32) {
#pragma unroll
      for (int i = 0; i < 2; ++i) {
        const float* p = Abase + arow[i] * K_ + (k0 + 32) + aslot[i] * 8;
        pre[i][0] = *(const float4*)p;
        pre[i][1] = *(const float4*)(p + 4);
      }
    }
    const int g = lane >> 4;
    bf16x8 af[4], bfr[4];
#pragma unroll
    for (int mi = 0; mi < 4; ++mi) {
      int r = wm * 64 + mi * 16 + (lane & 15);
      af[mi] = *(const bf16x8*)(&As[swz(r, g)]);
    }
#pragma unroll
    for (int ni = 0; ni < 4; ++ni) {
      int r = wn * 64 + ni * 16 + (lane & 15);
      bfr[ni] = *(const bf16x8*)(&Bs[swz(r, g)]);
    }
#pragma unroll
    for (int mi = 0; mi < 4; ++mi)
#pragma unroll
      for (int ni = 0; ni < 4; ++ni)
        acc[mi][ni] = __builtin_amdgcn_mfma_f32_16x16x32_bf16(af[mi], bfr[ni], acc[mi][ni], 0, 0, 0);
    __syncthreads();
  }

  energy_epilogue(acc, qp, v, energy, m0, n0, wm, wn, lane);
}

// ---------------------------------------------------------------- masked softmax
__global__ void softmax_kernel(const float* __restrict__ energy, const void* __restrict__ mask,
                               const int* __restrict__ flag, float* __restrict__ attn) {
  __shared__ float red[256];
  const int b = blockIdx.x, t = threadIdx.x;
  const int fl = *flag;
  float e[8];
#pragma unroll
  for (int i = 0; i < 8; ++i) {
    int s = i * 256 + t;
    int idx = b * S_ + s;
    bool m;
    if (fl == 1)      m = ((const unsigned char*)mask)[idx] != 0;
    else if (fl == 2) m = ((const float*)mask)[idx] != 0.f;
    else              m = ((const int*)mask)[idx] != 0;
    e[i] = m ? -INFINITY : energy[idx];
  }
  float mx = e[0];
#pragma unroll
  for (int i = 1; i < 8; ++i) mx = fmaxf(mx, e[i]);
  red[t] = mx; __syncthreads();
  for (int o = 128; o > 0; o >>= 1) { if (t < o) red[t] = fmaxf(red[t], red[t + o]); __syncthreads(); }
  mx = red[0];
  __syncthreads();
  const bool any = (mx > -INFINITY);
  float p[8]; float sum = 0.f;
#pragma unroll
  for (int i = 0; i < 8; ++i) {
    p[i] = (any && e[i] > -INFINITY) ? __expf(e[i] - mx) : 0.f;
    sum += p[i];
  }
  red[t] = sum; __syncthreads();
  for (int o = 128; o > 0; o >>= 1) { if (t < o) red[t] += red[t + o]; __syncthreads(); }
  sum = red[0];
  const float inv = (sum > 0.f) ? 1.f / sum : 0.f;
#pragma unroll
  for (int i = 0; i < 8; ++i) attn[b * S_ + i * 256 + t] = p[i] * inv;
}

// ---------------------------------------------------------------- context = attn @ keys
__global__ void context_kernel(const float* __restrict__ attn, const float* __restrict__ keys,
                               float* __restrict__ ctx) {
  const int b = blockIdx.y;
  const int sc = blockIdx.x;          // 16 chunks of 128 s
  const int t = threadIdx.x;          // k = 4t..4t+3
  const float* kb = keys + ((size_t)b * S_ + sc * 128) * K_;
  const float* ab = attn + b * S_ + sc * 128;
  float4 acc = {0.f, 0.f, 0.f, 0.f};
  for (int s = 0; s < 128; ++s) {
    float a = ab[s];                   // block-uniform
    if (a != 0.f) {                    // skip padded positions entirely
      float4 kv = *(const float4*)(kb + (size_t)s * K_ + t * 4);
      acc.x += a * kv.x; acc.y += a * kv.y; acc.z += a * kv.z; acc.w += a * kv.w;
    }
  }
  float* cb = ctx + b * K_ + t * 4;
  atomicAdd(cb + 0, acc.x);
  atomicAdd(cb + 1, acc.y);
  atomicAdd(cb + 2, acc.z);
  atomicAdd(cb + 3, acc.w);
}

// ---------------------------------------------------------------- launch
extern "C" void kernel_launch(void* const* d_in, const int* in_sizes, int n_in,
                              void* d_out, int out_size, void* d_ws, size_t ws_size,
                              hipStream_t stream) {
  (void)in_sizes; (void)n_in; (void)out_size;
  const float* query = (const float*)d_in[0];
  const float* keys  = (const float*)d_in[1];
  const void*  mask  = d_in[2];
  const float* Wq    = (const float*)d_in[3];
  const float* Wk    = (const float*)d_in[4];
  const float* v     = (const float*)d_in[5];

  float* ctx  = (float*)d_out;             // [64][1024]
  float* attn = (float*)d_out + B_ * K_;   // [64][2048]

  char* ws = (char*)d_ws;
  float*          energy = (float*)ws;                              // 512 KiB
  float*          qp     = (float*)(ws + (512 << 10));              // 256 KiB
  unsigned short* wkb    = (unsigned short*)(ws + (768 << 10));     // 2 MiB
  int*            flag   = (int*)(ws + (768 << 10) + (2 << 20));
  __bf16*         kb16   = (__bf16*)(ws + (4 << 20));               // 256 MiB (optional)

  const size_t need_big = (size_t)(4 << 20) + (size_t)M_ * K_ * 2;
  const bool big = ws_size >= need_big;

  hipMemsetAsync(energy, 0, (size_t)M_ * 4, stream);
  hipMemsetAsync(ctx, 0, (size_t)B_ * K_ * 4, stream);
  detect_mask<<<1, 256, 0, stream>>>((const unsigned int*)mask, flag);
  convert_wk<<<(H_ * K_ / 4) / 256, 256, 0, stream>>>(Wk, wkb);
  qp_kernel<<<B_, 256, 0, stream>>>(query, Wq, qp);
  if (big) {
    convert_keys<<<4096, 256, 0, stream>>>(keys, kb16, (long)M_ * K_ / 8);
    gemm_energy_b16<<<(M_ / 128) * (H_ / 128), 256, 0, stream>>>(
        kb16, (const __bf16*)wkb, qp, v, energy);
  } else {
    gemm_energy<<<(M_ / 128) * (H_ / 128), 256, 0, stream>>>(
        keys, (const __bf16*)wkb, qp, v, energy);
  }
  softmax_kernel<<<B_, 256, 0, stream>>>(energy, mask, flag, attn);
  context_kernel<<<dim3(S_ / 128, B_), 256, 0, stream>>>(attn, keys, ctx);
}

// Round 8
// 627.554 us; speedup vs baseline: 1.4547x; 1.1022x over previous
//
#include <hip/hip_runtime.h>
#include <math.h>

#define B_ 64
#define S_ 2048
#define H_ 1024
#define K_ 1024
#define M_ (B_*S_)   // 131072 rows of the big GEMM

using f32x4   = __attribute__((ext_vector_type(4))) float;
using bf16x8  = __attribute__((ext_vector_type(8))) __bf16;

__device__ __forceinline__ unsigned short f2b(float f) {
  unsigned int u = __float_as_uint(f);
  u += 0x7fffu + ((u >> 16) & 1u);   // RNE
  return (unsigned short)(u >> 16);
}

// tanh(x) = (e^2x - 1)/(e^2x + 1); clamp so t stays finite (tanh saturated anyway)
__device__ __forceinline__ float fast_tanh(float x) {
  float xc = fminf(fmaxf(x, -15.f), 15.f);
  float t = __expf(2.f * xc);
  return (t - 1.f) * __builtin_amdgcn_rcpf(t + 1.f);
}

typedef __attribute__((address_space(1))) void gvoid_t;
typedef __attribute__((address_space(3))) void lvoid_t;

__device__ __forceinline__ void async16(const void* g, void* l) {
  __builtin_amdgcn_global_load_lds((gvoid_t*)g, (lvoid_t*)l, 16, 0, 0);
}

// XOR-swizzled LDS element offset for (row r, 16B-slot sl) in a [128][32] bf16 tile
__device__ __forceinline__ int swz(int r, int sl) {
  return r * 32 + ((sl ^ ((r >> 1) & 3)) << 3);
}

// mask decode shared by all mask readers
__device__ __forceinline__ bool mask_at(const void* mask, int fl, int idx) {
  if (fl == 1)      return ((const unsigned char*)mask)[idx] != 0;
  else if (fl == 2) return ((const float*)mask)[idx] != 0.f;
  else              return ((const int*)mask)[idx] != 0;
}

// misc layout (ints): [0]=flag [1]=Mp (compact count) [2]=Mpr (rounded to 128)
//                     [16..144)=blocksum  [144..272)=blockoff

// ---------------------------------------------------------------- mask dtype
__global__ void detect_mask(const unsigned int* __restrict__ m, int* __restrict__ misc) {
  __shared__ int red[256];
  int t = threadIdx.x;
  int f = 0;
  for (int i = 0; i < 32; ++i) {
    unsigned int w = m[t * 32 + i];
    if (w > 1u) f |= 1;
    if (w != 0u && w != 0x3f800000u) f |= 2;
  }
  red[t] = f;
  __syncthreads();
  for (int o = 128; o > 0; o >>= 1) { if (t < o) red[t] |= red[t + o]; __syncthreads(); }
  if (t == 0) {
    int g = red[0];
    misc[0] = ((g & 1) == 0) ? 0 : (((g & 2) == 0) ? 2 : 1);
  }
}

// ---------------------------------------------------------------- compaction scans
__global__ void mask_count(const void* __restrict__ mask, int* __restrict__ misc) {
  __shared__ int red[256];
  const int fl = misc[0];
  const int t = threadIdx.x, blk = blockIdx.x;
  int cnt = 0;
#pragma unroll
  for (int i = 0; i < 4; ++i)
    cnt += mask_at(mask, fl, blk * 1024 + t * 4 + i) ? 0 : 1;
  red[t] = cnt; __syncthreads();
  for (int o = 128; o > 0; o >>= 1) { if (t < o) red[t] += red[t + o]; __syncthreads(); }
  if (t == 0) misc[16 + blk] = red[0];
}

__global__ void mask_scan(int* __restrict__ misc) {
  if (threadIdx.x == 0) {
    int acc = 0;
    for (int i = 0; i < 128; ++i) { misc[144 + i] = acc; acc += misc[16 + i]; }
    misc[1] = acc;
    misc[2] = (acc + 127) & ~127;
  }
}

__global__ void mask_writeidx(const void* __restrict__ mask, const int* __restrict__ misc,
                              int* __restrict__ ridx) {
  __shared__ int sc[256];
  const int fl = misc[0];
  const int t = threadIdx.x, blk = blockIdx.x;
  int um[4]; int cnt = 0;
#pragma unroll
  for (int i = 0; i < 4; ++i) {
    um[i] = mask_at(mask, fl, blk * 1024 + t * 4 + i) ? 0 : 1;
    cnt += um[i];
  }
  sc[t] = cnt; __syncthreads();
  for (int o = 1; o < 256; o <<= 1) {
    int v = (t >= o) ? sc[t - o] : 0;
    __syncthreads();
    sc[t] += v;
    __syncthreads();
  }
  int base = misc[144 + blk] + sc[t] - cnt;   // exclusive prefix
#pragma unroll
  for (int i = 0; i < 4; ++i)
    if (um[i]) ridx[base++] = blk * 1024 + t * 4 + i;
}

// ---------------------------------------------------------------- compacted keys -> bf16
__global__ void convert_keys_compact(const float* __restrict__ keys,
                                     const int* __restrict__ misc,
                                     const int* __restrict__ ridx,
                                     __bf16* __restrict__ dst) {
  const int mp = misc[1];
  const int j = blockIdx.x * 2 + (threadIdx.x >> 7);
  if (j >= mp) return;
  const int lane = threadIdx.x & 127;
  const float* src = keys + (size_t)ridx[j] * K_ + lane * 8;
  float4 a = *(const float4*)src, b = *(const float4*)(src + 4);
  bf16x8 u;
  u[0] = (__bf16)a.x; u[1] = (__bf16)a.y; u[2] = (__bf16)a.z; u[3] = (__bf16)a.w;
  u[4] = (__bf16)b.x; u[5] = (__bf16)b.y; u[6] = (__bf16)b.z; u[7] = (__bf16)b.w;
  *(bf16x8*)(dst + (size_t)j * K_ + lane * 8) = u;
}

__global__ void pad_zero(const int* __restrict__ misc, __bf16* __restrict__ dst) {
  const int mp = misc[1], mpr = misc[2];
  const int row = mp + blockIdx.x;
  if (row >= mpr) return;
  ushort4 z = {0, 0, 0, 0};
  *(ushort4*)((unsigned short*)dst + (size_t)row * K_ + threadIdx.x * 4) = z;
}

// ---------------------------------------------------------------- Wk -> bf16
__global__ void convert_wk(const float* __restrict__ src, unsigned short* __restrict__ dst) {
  int i = blockIdx.x * blockDim.x + threadIdx.x;
  float4 v = ((const float4*)src)[i];
  ushort4 o;
  o.x = f2b(v.x); o.y = f2b(v.y); o.z = f2b(v.z); o.w = f2b(v.w);
  *(ushort4*)(dst + (size_t)i * 4) = o;
}

// ---------------------------------------------------------------- qp = query @ Wq.T
__global__ void qp_kernel(const float* __restrict__ query, const float* __restrict__ Wq,
                          float* __restrict__ qp) {
  __shared__ float qs[1024];
  const int b = blockIdx.x, t = threadIdx.x;
  ((float4*)qs)[t] = ((const float4*)(query + b * 1024))[t];
  __syncthreads();
#pragma unroll
  for (int i = 0; i < 4; ++i) {
    int h = t + i * 256;
    const float4* wr = (const float4*)(Wq + h * 1024);
    float s = 0.f;
    for (int q4 = 0; q4 < 256; ++q4) {
      float4 w = wr[q4];
      float4 q = ((const float4*)qs)[q4];
      s += w.x * q.x + w.y * q.y + w.z * q.z + w.w * q.w;
    }
    qp[b * 1024 + h] = s;
  }
}

// ---------------------------------------------------------------- GEMM+energy, compacted bf16
// R7-proven m97 structure (both operands via global_load_lds, 2 barriers/step,
// both-sides swizzle). Operates on compacted rows; epilogue scatters via ridx.
__global__ __launch_bounds__(256, 4) void gemm_energy_c(
    const __bf16* __restrict__ kb,           // [Mpr][1024] compacted bf16 keys
    const __bf16* __restrict__ wk,           // [1024][1024] bf16 Wk
    const float* __restrict__ qp,            // [64][1024]
    const float* __restrict__ v,             // [1024]
    float* __restrict__ energy,              // [M_] (original row ids)
    const int* __restrict__ misc,
    const int* __restrict__ ridx) {
  __shared__ __align__(16) __bf16 As[128 * 32];
  __shared__ __align__(16) __bf16 Bs[128 * 32];

  const int tid  = threadIdx.x;
  const int w    = tid >> 6;
  const int lane = tid & 63;

  const int orig = blockIdx.x;                   // 0..8191
  const int wgid = (orig & 7) * 1024 + (orig >> 3);
  const int m0 = (wgid >> 3) * 128;
  const int n0 = (wgid & 7) * 128;

  const int mpr = misc[2];
  if (m0 >= mpr) return;                          // compacted: most blocks exit
  const int mp = misc[1];

  const int wm = w >> 1, wn = w & 1;

  f32x4 acc[4][4] = {};

  // staging geometry: 512 chunks of 8 bf16 per 128x32 tile; this thread owns 2
  int srow[2], soff[2], ldst[2];
#pragma unroll
  for (int j = 0; j < 2; ++j) {
    int c = tid + j * 256;
    srow[j] = c >> 2;
    soff[j] = (((c & 3) ^ ((srow[j] >> 1) & 3)) << 3);   // pre-swizzled source slot
    ldst[j] = (j * 256 + w * 64) * 8;                     // linear wave-uniform dest
  }
  const __bf16* Ab = kb + (size_t)m0 * K_;
  const __bf16* Bb = wk + (size_t)n0 * K_;

  for (int kt = 0; kt < 32; ++kt) {
    const int k0 = kt * 32;
#pragma unroll
    for (int j = 0; j < 2; ++j)
      async16(Ab + (size_t)srow[j] * K_ + k0 + soff[j], &As[ldst[j]]);
#pragma unroll
    for (int j = 0; j < 2; ++j)
      async16(Bb + (size_t)srow[j] * K_ + k0 + soff[j], &Bs[ldst[j]]);
    __syncthreads();
    const int g = lane >> 4;
    bf16x8 af[4], bfr[4];
#pragma unroll
    for (int mi = 0; mi < 4; ++mi) {
      int r = wm * 64 + mi * 16 + (lane & 15);
      af[mi] = *(const bf16x8*)(&As[swz(r, g)]);
    }
#pragma unroll
    for (int ni = 0; ni < 4; ++ni) {
      int r = wn * 64 + ni * 16 + (lane & 15);
      bfr[ni] = *(const bf16x8*)(&Bs[swz(r, g)]);
    }
#pragma unroll
    for (int mi = 0; mi < 4; ++mi)
#pragma unroll
      for (int ni = 0; ni < 4; ++ni)
        acc[mi][ni] = __builtin_amdgcn_mfma_f32_16x16x32_bf16(af[mi], bfr[ni], acc[mi][ni], 0, 0, 0);
    __syncthreads();
  }

  // epilogue with ridx indirection: row->original row (batch for qp, energy idx)
  float vv[4]; int hh[4];
#pragma unroll
  for (int ni = 0; ni < 4; ++ni) {
    hh[ni] = n0 + wn * 64 + ni * 16 + (lane & 15);
    vv[ni] = v[hh[ni]];
  }
#pragma unroll
  for (int mi = 0; mi < 4; ++mi) {
    const int rowbase = m0 + wm * 64 + mi * 16 + (lane >> 4) * 4;
    int oro[4];
#pragma unroll
    for (int rr = 0; rr < 4; ++rr) {
      int row = rowbase + rr;
      oro[rr] = (row < mp) ? ridx[row] : -1;
    }
    float ps[4] = {0.f, 0.f, 0.f, 0.f};
#pragma unroll
    for (int ni = 0; ni < 4; ++ni)
#pragma unroll
      for (int rr = 0; rr < 4; ++rr) {
        int bb = (oro[rr] >= 0 ? oro[rr] : 0) >> 11;
        ps[rr] += fast_tanh(acc[mi][ni][rr] + qp[bb * H_ + hh[ni]]) * vv[ni];
      }
#pragma unroll
    for (int off = 1; off < 16; off <<= 1)
#pragma unroll
      for (int rr = 0; rr < 4; ++rr)
        ps[rr] += __shfl_xor(ps[rr], off, 64);
    if ((lane & 15) == 0) {
#pragma unroll
      for (int rr = 0; rr < 4; ++rr)
        if (oro[rr] >= 0) atomicAdd(&energy[oro[rr]], ps[rr]);
    }
  }
}

// ---------------------------------------------------------------- fallback GEMM (f32 keys, full M)
__global__ __launch_bounds__(256) void gemm_energy(
    const float* __restrict__ keys, const __bf16* __restrict__ wk,
    const float* __restrict__ qp, const float* __restrict__ v,
    float* __restrict__ energy) {
  __shared__ __align__(16) __bf16 As[128 * 32];
  __shared__ __align__(16) __bf16 Bs[128 * 32];

  const int tid  = threadIdx.x;
  const int w    = tid >> 6;
  const int lane = tid & 63;

  const int orig = blockIdx.x;
  const int wgid = (orig & 7) * 1024 + (orig >> 3);
  const int m0 = (wgid >> 3) * 128;
  const int n0 = (wgid & 7) * 128;

  const int wm = w >> 1, wn = w & 1;

  f32x4 acc[4][4] = {};

  int arow[2], aslot[2];
#pragma unroll
  for (int i = 0; i < 2; ++i) {
    int c = tid + i * 256;
    arow[i]  = c >> 2;
    aslot[i] = c & 3;
  }
  const float* Abase = keys + (size_t)m0 * K_;

  int brow[2], bs_src[2], bs_dst[2];
#pragma unroll
  for (int j = 0; j < 2; ++j) {
    int flat = w * 1024 + j * 512 + lane * 8;
    brow[j]   = flat >> 5;
    bs_src[j] = (((flat >> 3) & 3) ^ ((brow[j] >> 1) & 3)) * 8;
    bs_dst[j] = w * 1024 + j * 512;
  }

  float4 pre[2][2];
#pragma unroll
  for (int i = 0; i < 2; ++i) {
    const float* p = Abase + arow[i] * K_ + aslot[i] * 8;
    pre[i][0] = *(const float4*)p;
    pre[i][1] = *(const float4*)(p + 4);
  }

  for (int kt = 0; kt < 32; ++kt) {
    const int k0 = kt * 32;
#pragma unroll
    for (int i = 0; i < 2; ++i) {
      bf16x8 u;
      u[0] = (__bf16)pre[i][0].x; u[1] = (__bf16)pre[i][0].y;
      u[2] = (__bf16)pre[i][0].z; u[3] = (__bf16)pre[i][0].w;
      u[4] = (__bf16)pre[i][1].x; u[5] = (__bf16)pre[i][1].y;
      u[6] = (__bf16)pre[i][1].z; u[7] = (__bf16)pre[i][1].w;
      *(bf16x8*)(&As[swz(arow[i], aslot[i])]) = u;
    }
#pragma unroll
    for (int j = 0; j < 2; ++j)
      async16(wk + (size_t)(n0 + brow[j]) * K_ + k0 + bs_src[j], &Bs[bs_dst[j]]);
    __syncthreads();
    if (kt + 1 < 32) {
#pragma unroll
      for (int i = 0; i < 2; ++i) {
        const float* p = Abase + arow[i] * K_ + (k0 + 32) + aslot[i] * 8;
        pre[i][0] = *(const float4*)p;
        pre[i][1] = *(const float4*)(p + 4);
      }
    }
    const int g = lane >> 4;
    bf16x8 af[4], bfr[4];
#pragma unroll
    for (int mi = 0; mi < 4; ++mi) {
      int r = wm * 64 + mi * 16 + (lane & 15);
      af[mi] = *(const bf16x8*)(&As[swz(r, g)]);
    }
#pragma unroll
    for (int ni = 0; ni < 4; ++ni) {
      int r = wn * 64 + ni * 16 + (lane & 15);
      bfr[ni] = *(const bf16x8*)(&Bs[swz(r, g)]);
    }
#pragma unroll
    for (int mi = 0; mi < 4; ++mi)
#pragma unroll
      for (int ni = 0; ni < 4; ++ni)
        acc[mi][ni] = __builtin_amdgcn_mfma_f32_16x16x32_bf16(af[mi], bfr[ni], acc[mi][ni], 0, 0, 0);
    __syncthreads();
  }

  const int bb = m0 >> 11;
  float qpv[4], vv[4];
#pragma unroll
  for (int ni = 0; ni < 4; ++ni) {
    int h = n0 + wn * 64 + ni * 16 + (lane & 15);
    qpv[ni] = qp[bb * H_ + h];
    vv[ni]  = v[h];
  }
#pragma unroll
  for (int mi = 0; mi < 4; ++mi) {
    float ps[4] = {0.f, 0.f, 0.f, 0.f};
#pragma unroll
    for (int ni = 0; ni < 4; ++ni)
#pragma unroll
      for (int rr = 0; rr < 4; ++rr)
        ps[rr] += fast_tanh(acc[mi][ni][rr] + qpv[ni]) * vv[ni];
#pragma unroll
    for (int off = 1; off < 16; off <<= 1)
#pragma unroll
      for (int rr = 0; rr < 4; ++rr)
        ps[rr] += __shfl_xor(ps[rr], off, 64);
    if ((lane & 15) == 0) {
      int rowbase = m0 + wm * 64 + mi * 16 + (lane >> 4) * 4;
#pragma unroll
      for (int rr = 0; rr < 4; ++rr)
        atomicAdd(&energy[rowbase + rr], ps[rr]);
    }
  }
}

// ---------------------------------------------------------------- masked softmax
__global__ void softmax_kernel(const float* __restrict__ energy, const void* __restrict__ mask,
                               const int* __restrict__ flag, float* __restrict__ attn) {
  __shared__ float red[256];
  const int b = blockIdx.x, t = threadIdx.x;
  const int fl = flag[0];
  float e[8];
#pragma unroll
  for (int i = 0; i < 8; ++i) {
    int idx = b * S_ + i * 256 + t;
    e[i] = mask_at(mask, fl, idx) ? -INFINITY : energy[idx];
  }
  float mx = e[0];
#pragma unroll
  for (int i = 1; i < 8; ++i) mx = fmaxf(mx, e[i]);
  red[t] = mx; __syncthreads();
  for (int o = 128; o > 0; o >>= 1) { if (t < o) red[t] = fmaxf(red[t], red[t + o]); __syncthreads(); }
  mx = red[0];
  __syncthreads();
  const bool any = (mx > -INFINITY);
  float p[8]; float sum = 0.f;
#pragma unroll
  for (int i = 0; i < 8; ++i) {
    p[i] = (any && e[i] > -INFINITY) ? __expf(e[i] - mx) : 0.f;
    sum += p[i];
  }
  red[t] = sum; __syncthreads();
  for (int o = 128; o > 0; o >>= 1) { if (t < o) red[t] += red[t + o]; __syncthreads(); }
  sum = red[0];
  const float inv = (sum > 0.f) ? 1.f / sum : 0.f;
#pragma unroll
  for (int i = 0; i < 8; ++i) attn[b * S_ + i * 256 + t] = p[i] * inv;
}

// ---------------------------------------------------------------- context = attn @ keys
__global__ void context_kernel(const float* __restrict__ attn, const float* __restrict__ keys,
                               float* __restrict__ ctx) {
  const int b = blockIdx.y;
  const int sc = blockIdx.x;          // 16 chunks of 128 s
  const int t = threadIdx.x;          // k = 4t..4t+3
  const float* kb = keys + ((size_t)b * S_ + sc * 128) * K_;
  const float* ab = attn + b * S_ + sc * 128;
  float4 acc = {0.f, 0.f, 0.f, 0.f};
  for (int s = 0; s < 128; ++s) {
    float a = ab[s];                   // block-uniform
    if (a != 0.f) {                    // skip padded positions entirely
      float4 kv = *(const float4*)(kb + (size_t)s * K_ + t * 4);
      acc.x += a * kv.x; acc.y += a * kv.y; acc.z += a * kv.z; acc.w += a * kv.w;
    }
  }
  float* cb = ctx + b * K_ + t * 4;
  atomicAdd(cb + 0, acc.x);
  atomicAdd(cb + 1, acc.y);
  atomicAdd(cb + 2, acc.z);
  atomicAdd(cb + 3, acc.w);
}

// ---------------------------------------------------------------- launch
extern "C" void kernel_launch(void* const* d_in, const int* in_sizes, int n_in,
                              void* d_out, int out_size, void* d_ws, size_t ws_size,
                              hipStream_t stream) {
  (void)in_sizes; (void)n_in; (void)out_size;
  const float* query = (const float*)d_in[0];
  const float* keys  = (const float*)d_in[1];
  const void*  mask  = d_in[2];
  const float* Wq    = (const float*)d_in[3];
  const float* Wk    = (const float*)d_in[4];
  const float* v     = (const float*)d_in[5];

  float* ctx  = (float*)d_out;             // [64][1024]
  float* attn = (float*)d_out + B_ * K_;   // [64][2048]

  char* ws = (char*)d_ws;
  float*          energy = (float*)ws;                              // 512 KiB
  float*          qp     = (float*)(ws + (512 << 10));              // 256 KiB
  unsigned short* wkb    = (unsigned short*)(ws + (768 << 10));     // 2 MiB
  int*            misc   = (int*)(ws + (768 << 10) + (2 << 20));    // 4 KiB
  int*            ridx   = (int*)(ws + (3 << 20));                  // 512 KiB
  __bf16*         kb16   = (__bf16*)(ws + (4 << 20));               // 256 MiB (optional)

  const size_t need_big = (size_t)(4 << 20) + (size_t)M_ * K_ * 2;
  const bool big = ws_size >= need_big;

  hipMemsetAsync(energy, 0, (size_t)M_ * 4, stream);
  hipMemsetAsync(ctx, 0, (size_t)B_ * K_ * 4, stream);
  detect_mask<<<1, 256, 0, stream>>>((const unsigned int*)mask, misc);
  convert_wk<<<(H_ * K_ / 4) / 256, 256, 0, stream>>>(Wk, wkb);
  qp_kernel<<<B_, 256, 0, stream>>>(query, Wq, qp);
  if (big) {
    mask_count<<<128, 256, 0, stream>>>(mask, misc);
    mask_scan<<<1, 64, 0, stream>>>(misc);
    mask_writeidx<<<128, 256, 0, stream>>>(mask, misc, ridx);
    convert_keys_compact<<<M_ / 2, 256, 0, stream>>>(keys, misc, ridx, kb16);
    pad_zero<<<128, 256, 0, stream>>>(misc, kb16);
    gemm_energy_c<<<(M_ / 128) * (H_ / 128), 256, 0, stream>>>(
        kb16, (const __bf16*)wkb, qp, v, energy, misc, ridx);
  } else {
    gemm_energy<<<(M_ / 128) * (H_ / 128), 256, 0, stream>>>(
        keys, (const __bf16*)wkb, qp, v, energy);
  }
  softmax_kernel<<<B_, 256, 0, stream>>>(energy, mask, misc, attn);
  context_kernel<<<dim3(S_ / 128, B_), 256, 0, stream>>>(attn, keys, ctx);
}

// Round 9
// 453.190 us; speedup vs baseline: 2.0144x; 1.3847x over previous
//
#include <hip/hip_runtime.h>
#include <math.h>

#define B_ 64
#define S_ 2048
#define H_ 1024
#define K_ 1024
#define M_ (B_*S_)   // 131072 rows of the big GEMM

using f32x4   = __attribute__((ext_vector_type(4))) float;
using bf16x8  = __attribute__((ext_vector_type(8))) __bf16;

__device__ __forceinline__ unsigned short f2b(float f) {
  unsigned int u = __float_as_uint(f);
  u += 0x7fffu + ((u >> 16) & 1u);   // RNE
  return (unsigned short)(u >> 16);
}

// tanh(x) = (e^2x - 1)/(e^2x + 1); clamp so t stays finite (tanh saturated anyway)
__device__ __forceinline__ float fast_tanh(float x) {
  float xc = fminf(fmaxf(x, -15.f), 15.f);
  float t = __expf(2.f * xc);
  return (t - 1.f) * __builtin_amdgcn_rcpf(t + 1.f);
}

typedef __attribute__((address_space(1))) void gvoid_t;
typedef __attribute__((address_space(3))) void lvoid_t;

__device__ __forceinline__ void async16(const void* g, void* l) {
  __builtin_amdgcn_global_load_lds((gvoid_t*)g, (lvoid_t*)l, 16, 0, 0);
}

// XOR-swizzled LDS element offset for (row r, 16B-slot sl) in a [128][32] bf16 tile
__device__ __forceinline__ int swz(int r, int sl) {
  return r * 32 + ((sl ^ ((r >> 1) & 3)) << 3);
}

// mask decode shared by all mask readers
__device__ __forceinline__ bool mask_at(const void* mask, int fl, int idx) {
  if (fl == 1)      return ((const unsigned char*)mask)[idx] != 0;
  else if (fl == 2) return ((const float*)mask)[idx] != 0.f;
  else              return ((const int*)mask)[idx] != 0;
}

// misc layout (ints): [0]=flag [1]=Mp (compact count) [2]=Mpr (rounded to 128)
//                     [16..144)=blocksum  [144..272)=blockoff

// ---------------------------------------------------------------- mask dtype
__global__ void detect_mask(const unsigned int* __restrict__ m, int* __restrict__ misc) {
  __shared__ int red[256];
  int t = threadIdx.x;
  int f = 0;
  for (int i = 0; i < 32; ++i) {
    unsigned int w = m[t * 32 + i];
    if (w > 1u) f |= 1;
    if (w != 0u && w != 0x3f800000u) f |= 2;
  }
  red[t] = f;
  __syncthreads();
  for (int o = 128; o > 0; o >>= 1) { if (t < o) red[t] |= red[t + o]; __syncthreads(); }
  if (t == 0) {
    int g = red[0];
    misc[0] = ((g & 1) == 0) ? 0 : (((g & 2) == 0) ? 2 : 1);
  }
}

// ---------------------------------------------------------------- compaction scans
__global__ void mask_count(const void* __restrict__ mask, int* __restrict__ misc) {
  __shared__ int red[256];
  const int fl = misc[0];
  const int t = threadIdx.x, blk = blockIdx.x;
  int cnt = 0;
#pragma unroll
  for (int i = 0; i < 4; ++i)
    cnt += mask_at(mask, fl, blk * 1024 + t * 4 + i) ? 0 : 1;
  red[t] = cnt; __syncthreads();
  for (int o = 128; o > 0; o >>= 1) { if (t < o) red[t] += red[t + o]; __syncthreads(); }
  if (t == 0) misc[16 + blk] = red[0];
}

__global__ void mask_scan(int* __restrict__ misc) {
  if (threadIdx.x == 0) {
    int acc = 0;
    for (int i = 0; i < 128; ++i) { misc[144 + i] = acc; acc += misc[16 + i]; }
    misc[1] = acc;
    misc[2] = (acc + 127) & ~127;
  }
}

__global__ void mask_writeidx(const void* __restrict__ mask, const int* __restrict__ misc,
                              int* __restrict__ ridx) {
  __shared__ int sc[256];
  const int fl = misc[0];
  const int t = threadIdx.x, blk = blockIdx.x;
  int um[4]; int cnt = 0;
#pragma unroll
  for (int i = 0; i < 4; ++i) {
    um[i] = mask_at(mask, fl, blk * 1024 + t * 4 + i) ? 0 : 1;
    cnt += um[i];
  }
  sc[t] = cnt; __syncthreads();
  for (int o = 1; o < 256; o <<= 1) {
    int v = (t >= o) ? sc[t - o] : 0;
    __syncthreads();
    sc[t] += v;
    __syncthreads();
  }
  int base = misc[144 + blk] + sc[t] - cnt;   // exclusive prefix
#pragma unroll
  for (int i = 0; i < 4; ++i)
    if (um[i]) ridx[base++] = blk * 1024 + t * 4 + i;
}

// ---------------------------------------------------------------- compacted keys -> bf16
__global__ void convert_keys_compact(const float* __restrict__ keys,
                                     const int* __restrict__ misc,
                                     const int* __restrict__ ridx,
                                     __bf16* __restrict__ dst) {
  const int mp = misc[1];
  const int j = blockIdx.x * 2 + (threadIdx.x >> 7);
  if (j >= mp) return;
  const int lane = threadIdx.x & 127;
  const float* src = keys + (size_t)ridx[j] * K_ + lane * 8;
  float4 a = *(const float4*)src, b = *(const float4*)(src + 4);
  bf16x8 u;
  u[0] = (__bf16)a.x; u[1] = (__bf16)a.y; u[2] = (__bf16)a.z; u[3] = (__bf16)a.w;
  u[4] = (__bf16)b.x; u[5] = (__bf16)b.y; u[6] = (__bf16)b.z; u[7] = (__bf16)b.w;
  *(bf16x8*)(dst + (size_t)j * K_ + lane * 8) = u;
}

__global__ void pad_zero(const int* __restrict__ misc, __bf16* __restrict__ dst) {
  const int mp = misc[1], mpr = misc[2];
  const int row = mp + blockIdx.x;
  if (row >= mpr) return;
  ushort4 z = {0, 0, 0, 0};
  *(ushort4*)((unsigned short*)dst + (size_t)row * K_ + threadIdx.x * 4) = z;
}

// ---------------------------------------------------------------- Wk -> bf16
__global__ void convert_wk(const float* __restrict__ src, unsigned short* __restrict__ dst) {
  int i = blockIdx.x * blockDim.x + threadIdx.x;
  float4 v = ((const float4*)src)[i];
  ushort4 o;
  o.x = f2b(v.x); o.y = f2b(v.y); o.z = f2b(v.z); o.w = f2b(v.w);
  *(ushort4*)(dst + (size_t)i * 4) = o;
}

// ---------------------------------------------------------------- qp = query @ Wq.T
__global__ void qp_kernel(const float* __restrict__ query, const float* __restrict__ Wq,
                          float* __restrict__ qp) {
  __shared__ float qs[1024];
  const int b = blockIdx.x, t = threadIdx.x;
  ((float4*)qs)[t] = ((const float4*)(query + b * 1024))[t];
  __syncthreads();
#pragma unroll
  for (int i = 0; i < 4; ++i) {
    int h = t + i * 256;
    const float4* wr = (const float4*)(Wq + h * 1024);
    float s = 0.f;
    for (int q4 = 0; q4 < 256; ++q4) {
      float4 w = wr[q4];
      float4 q = ((const float4*)qs)[q4];
      s += w.x * q.x + w.y * q.y + w.z * q.z + w.w * q.w;
    }
    qp[b * 1024 + h] = s;
  }
}

// ---------------------------------------------------------------- GEMM+energy, compacted bf16
// R7-proven m97 structure. NEW block mapping: x=orig&7 (XCD), j=orig>>3;
// n_tile=j&7, m_tile=x+8*(j>>3). All 8 n-tiles of an m-tile stay on one XCD
// (keys-panel L2 sharing) AND working m-tiles (m0 < mpr) spread over ALL XCDs
// regardless of compact count (fixes R8's half-idle-machine bug).
__global__ __launch_bounds__(256, 4) void gemm_energy_c(
    const __bf16* __restrict__ kb,           // [Mpr][1024] compacted bf16 keys
    const __bf16* __restrict__ wk,           // [1024][1024] bf16 Wk
    const float* __restrict__ qp,            // [64][1024]
    const float* __restrict__ v,             // [1024]
    float* __restrict__ energy,              // [M_] (original row ids)
    const int* __restrict__ misc,
    const int* __restrict__ ridx) {
  __shared__ __align__(16) __bf16 As[128 * 32];
  __shared__ __align__(16) __bf16 Bs[128 * 32];

  const int tid  = threadIdx.x;
  const int w    = tid >> 6;
  const int lane = tid & 63;

  const int orig = blockIdx.x;                   // 0..8191
  const int x = orig & 7, j = orig >> 3;
  const int m0 = (x + 8 * (j >> 3)) * 128;
  const int n0 = (j & 7) * 128;

  const int mpr = misc[2];
  if (m0 >= mpr) return;                          // compacted: excess blocks exit
  const int mp = misc[1];

  const int wm = w >> 1, wn = w & 1;

  f32x4 acc[4][4] = {};

  // staging geometry: 512 chunks of 8 bf16 per 128x32 tile; this thread owns 2
  int srow[2], soff[2], ldst[2];
#pragma unroll
  for (int jj = 0; jj < 2; ++jj) {
    int c = tid + jj * 256;
    srow[jj] = c >> 2;
    soff[jj] = (((c & 3) ^ ((srow[jj] >> 1) & 3)) << 3);   // pre-swizzled source slot
    ldst[jj] = (jj * 256 + w * 64) * 8;                     // linear wave-uniform dest
  }
  const __bf16* Ab = kb + (size_t)m0 * K_;
  const __bf16* Bb = wk + (size_t)n0 * K_;

  for (int kt = 0; kt < 32; ++kt) {
    const int k0 = kt * 32;
#pragma unroll
    for (int jj = 0; jj < 2; ++jj)
      async16(Ab + (size_t)srow[jj] * K_ + k0 + soff[jj], &As[ldst[jj]]);
#pragma unroll
    for (int jj = 0; jj < 2; ++jj)
      async16(Bb + (size_t)srow[jj] * K_ + k0 + soff[jj], &Bs[ldst[jj]]);
    __syncthreads();
    const int g = lane >> 4;
    bf16x8 af[4], bfr[4];
#pragma unroll
    for (int mi = 0; mi < 4; ++mi) {
      int r = wm * 64 + mi * 16 + (lane & 15);
      af[mi] = *(const bf16x8*)(&As[swz(r, g)]);
    }
#pragma unroll
    for (int ni = 0; ni < 4; ++ni) {
      int r = wn * 64 + ni * 16 + (lane & 15);
      bfr[ni] = *(const bf16x8*)(&Bs[swz(r, g)]);
    }
#pragma unroll
    for (int mi = 0; mi < 4; ++mi)
#pragma unroll
      for (int ni = 0; ni < 4; ++ni)
        acc[mi][ni] = __builtin_amdgcn_mfma_f32_16x16x32_bf16(af[mi], bfr[ni], acc[mi][ni], 0, 0, 0);
    __syncthreads();
  }

  // epilogue with ridx indirection: row->original row (batch for qp, energy idx)
  float vv[4]; int hh[4];
#pragma unroll
  for (int ni = 0; ni < 4; ++ni) {
    hh[ni] = n0 + wn * 64 + ni * 16 + (lane & 15);
    vv[ni] = v[hh[ni]];
  }
#pragma unroll
  for (int mi = 0; mi < 4; ++mi) {
    const int rowbase = m0 + wm * 64 + mi * 16 + (lane >> 4) * 4;
    int oro[4];
#pragma unroll
    for (int rr = 0; rr < 4; ++rr) {
      int row = rowbase + rr;
      oro[rr] = (row < mp) ? ridx[row] : -1;
    }
    float ps[4] = {0.f, 0.f, 0.f, 0.f};
#pragma unroll
    for (int ni = 0; ni < 4; ++ni)
#pragma unroll
      for (int rr = 0; rr < 4; ++rr) {
        int bb = (oro[rr] >= 0 ? oro[rr] : 0) >> 11;
        ps[rr] += fast_tanh(acc[mi][ni][rr] + qp[bb * H_ + hh[ni]]) * vv[ni];
      }
#pragma unroll
    for (int off = 1; off < 16; off <<= 1)
#pragma unroll
      for (int rr = 0; rr < 4; ++rr)
        ps[rr] += __shfl_xor(ps[rr], off, 64);
    if ((lane & 15) == 0) {
#pragma unroll
      for (int rr = 0; rr < 4; ++rr)
        if (oro[rr] >= 0) atomicAdd(&energy[oro[rr]], ps[rr]);
    }
  }
}

// ---------------------------------------------------------------- fallback GEMM (f32 keys, full M)
__global__ __launch_bounds__(256) void gemm_energy(
    const float* __restrict__ keys, const __bf16* __restrict__ wk,
    const float* __restrict__ qp, const float* __restrict__ v,
    float* __restrict__ energy) {
  __shared__ __align__(16) __bf16 As[128 * 32];
  __shared__ __align__(16) __bf16 Bs[128 * 32];

  const int tid  = threadIdx.x;
  const int w    = tid >> 6;
  const int lane = tid & 63;

  const int orig = blockIdx.x;
  const int wgid = (orig & 7) * 1024 + (orig >> 3);
  const int m0 = (wgid >> 3) * 128;
  const int n0 = (wgid & 7) * 128;

  const int wm = w >> 1, wn = w & 1;

  f32x4 acc[4][4] = {};

  int arow[2], aslot[2];
#pragma unroll
  for (int i = 0; i < 2; ++i) {
    int c = tid + i * 256;
    arow[i]  = c >> 2;
    aslot[i] = c & 3;
  }
  const float* Abase = keys + (size_t)m0 * K_;

  int brow[2], bs_src[2], bs_dst[2];
#pragma unroll
  for (int j = 0; j < 2; ++j) {
    int flat = w * 1024 + j * 512 + lane * 8;
    brow[j]   = flat >> 5;
    bs_src[j] = (((flat >> 3) & 3) ^ ((brow[j] >> 1) & 3)) * 8;
    bs_dst[j] = w * 1024 + j * 512;
  }

  float4 pre[2][2];
#pragma unroll
  for (int i = 0; i < 2; ++i) {
    const float* p = Abase + arow[i] * K_ + aslot[i] * 8;
    pre[i][0] = *(const float4*)p;
    pre[i][1] = *(const float4*)(p + 4);
  }

  for (int kt = 0; kt < 32; ++kt) {
    const int k0 = kt * 32;
#pragma unroll
    for (int i = 0; i < 2; ++i) {
      bf16x8 u;
      u[0] = (__bf16)pre[i][0].x; u[1] = (__bf16)pre[i][0].y;
      u[2] = (__bf16)pre[i][0].z; u[3] = (__bf16)pre[i][0].w;
      u[4] = (__bf16)pre[i][1].x; u[5] = (__bf16)pre[i][1].y;
      u[6] = (__bf16)pre[i][1].z; u[7] = (__bf16)pre[i][1].w;
      *(bf16x8*)(&As[swz(arow[i], aslot[i])]) = u;
    }
#pragma unroll
    for (int j = 0; j < 2; ++j)
      async16(wk + (size_t)(n0 + brow[j]) * K_ + k0 + bs_src[j], &Bs[bs_dst[j]]);
    __syncthreads();
    if (kt + 1 < 32) {
#pragma unroll
      for (int i = 0; i < 2; ++i) {
        const float* p = Abase + arow[i] * K_ + (k0 + 32) + aslot[i] * 8;
        pre[i][0] = *(const float4*)p;
        pre[i][1] = *(const float4*)(p + 4);
      }
    }
    const int g = lane >> 4;
    bf16x8 af[4], bfr[4];
#pragma unroll
    for (int mi = 0; mi < 4; ++mi) {
      int r = wm * 64 + mi * 16 + (lane & 15);
      af[mi] = *(const bf16x8*)(&As[swz(r, g)]);
    }
#pragma unroll
    for (int ni = 0; ni < 4; ++ni) {
      int r = wn * 64 + ni * 16 + (lane & 15);
      bfr[ni] = *(const bf16x8*)(&Bs[swz(r, g)]);
    }
#pragma unroll
    for (int mi = 0; mi < 4; ++mi)
#pragma unroll
      for (int ni = 0; ni < 4; ++ni)
        acc[mi][ni] = __builtin_amdgcn_mfma_f32_16x16x32_bf16(af[mi], bfr[ni], acc[mi][ni], 0, 0, 0);
    __syncthreads();
  }

  const int bb = m0 >> 11;
  float qpv[4], vv[4];
#pragma unroll
  for (int ni = 0; ni < 4; ++ni) {
    int h = n0 + wn * 64 + ni * 16 + (lane & 15);
    qpv[ni] = qp[bb * H_ + h];
    vv[ni]  = v[h];
  }
#pragma unroll
  for (int mi = 0; mi < 4; ++mi) {
    float ps[4] = {0.f, 0.f, 0.f, 0.f};
#pragma unroll
    for (int ni = 0; ni < 4; ++ni)
#pragma unroll
      for (int rr = 0; rr < 4; ++rr)
        ps[rr] += fast_tanh(acc[mi][ni][rr] + qpv[ni]) * vv[ni];
#pragma unroll
    for (int off = 1; off < 16; off <<= 1)
#pragma unroll
      for (int rr = 0; rr < 4; ++rr)
        ps[rr] += __shfl_xor(ps[rr], off, 64);
    if ((lane & 15) == 0) {
      int rowbase = m0 + wm * 64 + mi * 16 + (lane >> 4) * 4;
#pragma unroll
      for (int rr = 0; rr < 4; ++rr)
        atomicAdd(&energy[rowbase + rr], ps[rr]);
    }
  }
}

// ---------------------------------------------------------------- masked softmax
__global__ void softmax_kernel(const float* __restrict__ energy, const void* __restrict__ mask,
                               const int* __restrict__ flag, float* __restrict__ attn) {
  __shared__ float red[256];
  const int b = blockIdx.x, t = threadIdx.x;
  const int fl = flag[0];
  float e[8];
#pragma unroll
  for (int i = 0; i < 8; ++i) {
    int idx = b * S_ + i * 256 + t;
    e[i] = mask_at(mask, fl, idx) ? -INFINITY : energy[idx];
  }
  float mx = e[0];
#pragma unroll
  for (int i = 1; i < 8; ++i) mx = fmaxf(mx, e[i]);
  red[t] = mx; __syncthreads();
  for (int o = 128; o > 0; o >>= 1) { if (t < o) red[t] = fmaxf(red[t], red[t + o]); __syncthreads(); }
  mx = red[0];
  __syncthreads();
  const bool any = (mx > -INFINITY);
  float p[8]; float sum = 0.f;
#pragma unroll
  for (int i = 0; i < 8; ++i) {
    p[i] = (any && e[i] > -INFINITY) ? __expf(e[i] - mx) : 0.f;
    sum += p[i];
  }
  red[t] = sum; __syncthreads();
  for (int o = 128; o > 0; o >>= 1) { if (t < o) red[t] += red[t + o]; __syncthreads(); }
  sum = red[0];
  const float inv = (sum > 0.f) ? 1.f / sum : 0.f;
#pragma unroll
  for (int i = 0; i < 8; ++i) attn[b * S_ + i * 256 + t] = p[i] * inv;
}

// ---------------------------------------------------------------- context over compacted bf16 keys
// ctx[b] += sum_j attn[ridx[j]] * kb16[j]; batch id monotonic in j -> flush on change.
__global__ void context_c(const float* __restrict__ attn, const __bf16* __restrict__ kb,
                          const int* __restrict__ misc, const int* __restrict__ ridx,
                          float* __restrict__ ctx) {
  const int mp = misc[1];
  const int j0 = blockIdx.x * 128;
  if (j0 >= mp) return;
  const int jend = (j0 + 128 < mp) ? j0 + 128 : mp;
  const int t = threadIdx.x;                 // k = 4t..4t+3
  const unsigned short* kbb = (const unsigned short*)kb;
  float4 acc = {0.f, 0.f, 0.f, 0.f};
  int curb = ridx[j0] >> 11;
  for (int j = j0; j < jend; ++j) {
    const int row = ridx[j];
    const int b = row >> 11;
    if (b != curb) {
      float* cb = ctx + curb * K_ + t * 4;
      atomicAdd(cb + 0, acc.x); atomicAdd(cb + 1, acc.y);
      atomicAdd(cb + 2, acc.z); atomicAdd(cb + 3, acc.w);
      acc.x = acc.y = acc.z = acc.w = 0.f;
      curb = b;
    }
    const float a = attn[row];
    if (a != 0.f) {
      ushort4 kv = *(const ushort4*)(kbb + (size_t)j * K_ + t * 4);
      acc.x += a * __uint_as_float((unsigned)kv.x << 16);
      acc.y += a * __uint_as_float((unsigned)kv.y << 16);
      acc.z += a * __uint_as_float((unsigned)kv.z << 16);
      acc.w += a * __uint_as_float((unsigned)kv.w << 16);
    }
  }
  float* cb = ctx + curb * K_ + t * 4;
  atomicAdd(cb + 0, acc.x); atomicAdd(cb + 1, acc.y);
  atomicAdd(cb + 2, acc.z); atomicAdd(cb + 3, acc.w);
}

// ---------------------------------------------------------------- fallback context (f32 keys)
__global__ void context_kernel(const float* __restrict__ attn, const float* __restrict__ keys,
                               float* __restrict__ ctx) {
  const int b = blockIdx.y;
  const int sc = blockIdx.x;
  const int t = threadIdx.x;
  const float* kb = keys + ((size_t)b * S_ + sc * 128) * K_;
  const float* ab = attn + b * S_ + sc * 128;
  float4 acc = {0.f, 0.f, 0.f, 0.f};
  for (int s = 0; s < 128; ++s) {
    float a = ab[s];
    if (a != 0.f) {
      float4 kv = *(const float4*)(kb + (size_t)s * K_ + t * 4);
      acc.x += a * kv.x; acc.y += a * kv.y; acc.z += a * kv.z; acc.w += a * kv.w;
    }
  }
  float* cb = ctx + b * K_ + t * 4;
  atomicAdd(cb + 0, acc.x);
  atomicAdd(cb + 1, acc.y);
  atomicAdd(cb + 2, acc.z);
  atomicAdd(cb + 3, acc.w);
}

// ---------------------------------------------------------------- launch
extern "C" void kernel_launch(void* const* d_in, const int* in_sizes, int n_in,
                              void* d_out, int out_size, void* d_ws, size_t ws_size,
                              hipStream_t stream) {
  (void)in_sizes; (void)n_in; (void)out_size;
  const float* query = (const float*)d_in[0];
  const float* keys  = (const float*)d_in[1];
  const void*  mask  = d_in[2];
  const float* Wq    = (const float*)d_in[3];
  const float* Wk    = (const float*)d_in[4];
  const float* v     = (const float*)d_in[5];

  float* ctx  = (float*)d_out;             // [64][1024]
  float* attn = (float*)d_out + B_ * K_;   // [64][2048]

  char* ws = (char*)d_ws;
  float*          energy = (float*)ws;                              // 512 KiB
  float*          qp     = (float*)(ws + (512 << 10));              // 256 KiB
  unsigned short* wkb    = (unsigned short*)(ws + (768 << 10));     // 2 MiB
  int*            misc   = (int*)(ws + (768 << 10) + (2 << 20));    // 4 KiB
  int*            ridx   = (int*)(ws + (3 << 20));                  // 512 KiB
  __bf16*         kb16   = (__bf16*)(ws + (4 << 20));               // 256 MiB (optional)

  const size_t need_big = (size_t)(4 << 20) + (size_t)M_ * K_ * 2;
  const bool big = ws_size >= need_big;

  hipMemsetAsync(energy, 0, (size_t)M_ * 4, stream);
  hipMemsetAsync(ctx, 0, (size_t)B_ * K_ * 4, stream);
  detect_mask<<<1, 256, 0, stream>>>((const unsigned int*)mask, misc);
  convert_wk<<<(H_ * K_ / 4) / 256, 256, 0, stream>>>(Wk, wkb);
  qp_kernel<<<B_, 256, 0, stream>>>(query, Wq, qp);
  if (big) {
    mask_count<<<128, 256, 0, stream>>>(mask, misc);
    mask_scan<<<1, 64, 0, stream>>>(misc);
    mask_writeidx<<<128, 256, 0, stream>>>(mask, misc, ridx);
    convert_keys_compact<<<M_ / 2, 256, 0, stream>>>(keys, misc, ridx, kb16);
    pad_zero<<<128, 256, 0, stream>>>(misc, kb16);
    gemm_energy_c<<<(M_ / 128) * (H_ / 128), 256, 0, stream>>>(
        kb16, (const __bf16*)wkb, qp, v, energy, misc, ridx);
    softmax_kernel<<<B_, 256, 0, stream>>>(energy, mask, misc, attn);
    context_c<<<M_ / 128, 256, 0, stream>>>(attn, kb16, misc, ridx, ctx);
  } else {
    gemm_energy<<<(M_ / 128) * (H_ / 128), 256, 0, stream>>>(
        keys, (const __bf16*)wkb, qp, v, energy);
    softmax_kernel<<<B_, 256, 0, stream>>>(energy, mask, misc, attn);
    context_kernel<<<dim3(S_ / 128, B_), 256, 0, stream>>>(attn, keys, ctx);
  }
}

// Round 10
// 439.600 us; speedup vs baseline: 2.0767x; 1.0309x over previous
//
#include <hip/hip_runtime.h>
#include <math.h>

#define B_ 64
#define S_ 2048
#define H_ 1024
#define K_ 1024
#define M_ (B_*S_)   // 131072 rows of the big GEMM

using f32x4   = __attribute__((ext_vector_type(4))) float;
using bf16x8  = __attribute__((ext_vector_type(8))) __bf16;

__device__ __forceinline__ unsigned short f2b(float f) {
  unsigned int u = __float_as_uint(f);
  u += 0x7fffu + ((u >> 16) & 1u);   // RNE
  return (unsigned short)(u >> 16);
}

// tanh(x) = (e^2x - 1)/(e^2x + 1); clamp so t stays finite (tanh saturated anyway)
__device__ __forceinline__ float fast_tanh(float x) {
  float xc = fminf(fmaxf(x, -15.f), 15.f);
  float t = __expf(2.f * xc);
  return (t - 1.f) * __builtin_amdgcn_rcpf(t + 1.f);
}

typedef __attribute__((address_space(1))) void gvoid_t;
typedef __attribute__((address_space(3))) void lvoid_t;

__device__ __forceinline__ void async16(const void* g, void* l) {
  __builtin_amdgcn_global_load_lds((gvoid_t*)g, (lvoid_t*)l, 16, 0, 0);
}

// bf16 B tile [128][32]: XOR-swizzled element offset for (row r, 16B-slot sl)
__device__ __forceinline__ int swz(int r, int sl) {
  return r * 32 + ((sl ^ ((r >> 1) & 3)) << 3);
}

// f32 A tile [128 rows][32 f32] = 8 chunks of 16B per row; chunk' = chunk ^ (r&7)
__device__ __forceinline__ int swzf(int r, int chunk) {
  return r * 32 + ((chunk ^ (r & 7)) << 2);   // float elements
}

// mask decode shared by all mask readers
__device__ __forceinline__ bool mask_at(const void* mask, int fl, int idx) {
  if (fl == 1)      return ((const unsigned char*)mask)[idx] != 0;
  else if (fl == 2) return ((const float*)mask)[idx] != 0.f;
  else              return ((const int*)mask)[idx] != 0;
}

// misc layout (ints): [0]=flag [1]=Mp (compact count) [2]=Mpr (rounded to 128)
//                     [16..144)=blocksum  [144..272)=blockoff

// ---------------------------------------------------------------- mask dtype
__global__ void detect_mask(const unsigned int* __restrict__ m, int* __restrict__ misc) {
  __shared__ int red[256];
  int t = threadIdx.x;
  int f = 0;
  for (int i = 0; i < 32; ++i) {
    unsigned int w = m[t * 32 + i];
    if (w > 1u) f |= 1;
    if (w != 0u && w != 0x3f800000u) f |= 2;
  }
  red[t] = f;
  __syncthreads();
  for (int o = 128; o > 0; o >>= 1) { if (t < o) red[t] |= red[t + o]; __syncthreads(); }
  if (t == 0) {
    int g = red[0];
    misc[0] = ((g & 1) == 0) ? 0 : (((g & 2) == 0) ? 2 : 1);
  }
}

// ---------------------------------------------------------------- compaction scans
__global__ void mask_count(const void* __restrict__ mask, int* __restrict__ misc) {
  __shared__ int red[256];
  const int fl = misc[0];
  const int t = threadIdx.x, blk = blockIdx.x;
  int cnt = 0;
#pragma unroll
  for (int i = 0; i < 4; ++i)
    cnt += mask_at(mask, fl, blk * 1024 + t * 4 + i) ? 0 : 1;
  red[t] = cnt; __syncthreads();
  for (int o = 128; o > 0; o >>= 1) { if (t < o) red[t] += red[t + o]; __syncthreads(); }
  if (t == 0) misc[16 + blk] = red[0];
}

__global__ void mask_scan(int* __restrict__ misc) {
  if (threadIdx.x == 0) {
    int acc = 0;
    for (int i = 0; i < 128; ++i) { misc[144 + i] = acc; acc += misc[16 + i]; }
    misc[1] = acc;
    misc[2] = (acc + 127) & ~127;
  }
}

__global__ void mask_writeidx(const void* __restrict__ mask, const int* __restrict__ misc,
                              int* __restrict__ ridx) {
  __shared__ int sc[256];
  const int fl = misc[0];
  const int t = threadIdx.x, blk = blockIdx.x;
  int um[4]; int cnt = 0;
#pragma unroll
  for (int i = 0; i < 4; ++i) {
    um[i] = mask_at(mask, fl, blk * 1024 + t * 4 + i) ? 0 : 1;
    cnt += um[i];
  }
  sc[t] = cnt; __syncthreads();
  for (int o = 1; o < 256; o <<= 1) {
    int v = (t >= o) ? sc[t - o] : 0;
    __syncthreads();
    sc[t] += v;
    __syncthreads();
  }
  int base = misc[144 + blk] + sc[t] - cnt;   // exclusive prefix
#pragma unroll
  for (int i = 0; i < 4; ++i)
    if (um[i]) ridx[base++] = blk * 1024 + t * 4 + i;
}

// ---------------------------------------------------------------- Wk -> bf16
__global__ void convert_wk(const float* __restrict__ src, unsigned short* __restrict__ dst) {
  int i = blockIdx.x * blockDim.x + threadIdx.x;
  float4 v = ((const float4*)src)[i];
  ushort4 o;
  o.x = f2b(v.x); o.y = f2b(v.y); o.z = f2b(v.z); o.w = f2b(v.w);
  *(ushort4*)(dst + (size_t)i * 4) = o;
}

// ---------------------------------------------------------------- qp = query @ Wq.T
__global__ void qp_kernel(const float* __restrict__ query, const float* __restrict__ Wq,
                          float* __restrict__ qp) {
  __shared__ float qs[1024];
  const int b = blockIdx.x, t = threadIdx.x;
  ((float4*)qs)[t] = ((const float4*)(query + b * 1024))[t];
  __syncthreads();
#pragma unroll
  for (int i = 0; i < 4; ++i) {
    int h = t + i * 256;
    const float4* wr = (const float4*)(Wq + h * 1024);
    float s = 0.f;
    for (int q4 = 0; q4 < 256; ++q4) {
      float4 w = wr[q4];
      float4 q = ((const float4*)qs)[q4];
      s += w.x * q.x + w.y * q.y + w.z * q.z + w.w * q.w;
    }
    qp[b * 1024 + h] = s;
  }
}

// ---------------------------------------------------------------- GEMM+energy, gather f32 A
// m97 structure; A gathered DIRECTLY from original f32 keys via per-lane
// global_load_lds source addresses (ridx indirection) -- no compact copy, no
// convert pass. A staged f32 into swizzled LDS, cvt to bf16 after ds_read.
// B (Wk bf16, L2-resident) staged as before. Pad rows read real data; their
// C-rows are discarded by the oro<0 guard (MFMA rows independent).
__global__ __launch_bounds__(256, 4) void gemm_energy_g(
    const float* __restrict__ keys,          // [M_][1024] f32 (original)
    const __bf16* __restrict__ wk,           // [1024][1024] bf16 Wk
    const float* __restrict__ qp,            // [64][1024]
    const float* __restrict__ v,             // [1024]
    float* __restrict__ energy,              // [M_] (original row ids)
    const int* __restrict__ misc,
    const int* __restrict__ ridx) {
  __shared__ __align__(16) float  Asf[128 * 32];   // 16 KB
  __shared__ __align__(16) __bf16 Bs[128 * 32];    //  8 KB

  const int tid  = threadIdx.x;
  const int w    = tid >> 6;
  const int lane = tid & 63;

  // XCD mapping (R9-proven): all 8 n-tiles of an m-tile on one XCD; working
  // m-tiles spread over all XCDs regardless of compact count.
  const int orig = blockIdx.x;                   // 0..8191
  const int x = orig & 7, j = orig >> 3;
  const int m0 = (x + 8 * (j >> 3)) * 128;
  const int n0 = (j & 7) * 128;

  const int mpr = misc[2];
  if (m0 >= mpr) return;
  const int mp = misc[1];

  const int wm = w >> 1, wn = w & 1;

  f32x4 acc[4][4] = {};

  // A staging: 1024 chunks of 16B (4 f32); this thread owns 4 (per-lane gather src)
  const float* asrc[4]; int adst[4];
#pragma unroll
  for (int i = 0; i < 4; ++i) {
    int c = tid + i * 256;            // = i*256 + w*64 + lane
    int r = c >> 3, cl = c & 7;
    int row = m0 + r;
    int oro = (row < mp) ? ridx[row] : ridx[mp - 1];   // clamp: pads discarded later
    asrc[i] = keys + (size_t)oro * K_ + ((cl ^ (r & 7)) << 2);
    adst[i] = (i * 256 + w * 64) * 4;  // wave-uniform float-element base
  }
  // B staging: 512 chunks of 16B (8 bf16); this thread owns 2
  const __bf16* bsrc[2]; int bdst[2];
#pragma unroll
  for (int jj = 0; jj < 2; ++jj) {
    int c = tid + jj * 256;
    int r = c >> 2;
    int soff = (((c & 3) ^ ((r >> 1) & 3)) << 3);
    bsrc[jj] = wk + (size_t)(n0 + r) * K_ + soff;
    bdst[jj] = (jj * 256 + w * 64) * 8;
  }

  for (int kt = 0; kt < 32; ++kt) {
    const int k0 = kt * 32;
#pragma unroll
    for (int i = 0; i < 4; ++i)
      async16(asrc[i] + k0, &Asf[adst[i]]);
#pragma unroll
    for (int jj = 0; jj < 2; ++jj)
      async16(bsrc[jj] + k0, &Bs[bdst[jj]]);
    __syncthreads();
    const int g = lane >> 4;
    bf16x8 af[4], bfr[4];
#pragma unroll
    for (int mi = 0; mi < 4; ++mi) {
      int r = wm * 64 + mi * 16 + (lane & 15);
      f32x4 lo = *(const f32x4*)(&Asf[swzf(r, 2 * g)]);
      f32x4 hi = *(const f32x4*)(&Asf[swzf(r, 2 * g + 1)]);
      bf16x8 u;
      u[0] = (__bf16)lo[0]; u[1] = (__bf16)lo[1]; u[2] = (__bf16)lo[2]; u[3] = (__bf16)lo[3];
      u[4] = (__bf16)hi[0]; u[5] = (__bf16)hi[1]; u[6] = (__bf16)hi[2]; u[7] = (__bf16)hi[3];
      af[mi] = u;
    }
#pragma unroll
    for (int ni = 0; ni < 4; ++ni) {
      int r = wn * 64 + ni * 16 + (lane & 15);
      bfr[ni] = *(const bf16x8*)(&Bs[swz(r, g)]);
    }
#pragma unroll
    for (int mi = 0; mi < 4; ++mi)
#pragma unroll
      for (int ni = 0; ni < 4; ++ni)
        acc[mi][ni] = __builtin_amdgcn_mfma_f32_16x16x32_bf16(af[mi], bfr[ni], acc[mi][ni], 0, 0, 0);
    __syncthreads();
  }

  // epilogue with ridx indirection (row -> original row for qp batch + energy)
  float vv[4]; int hh[4];
#pragma unroll
  for (int ni = 0; ni < 4; ++ni) {
    hh[ni] = n0 + wn * 64 + ni * 16 + (lane & 15);
    vv[ni] = v[hh[ni]];
  }
#pragma unroll
  for (int mi = 0; mi < 4; ++mi) {
    const int rowbase = m0 + wm * 64 + mi * 16 + (lane >> 4) * 4;
    int oro[4];
#pragma unroll
    for (int rr = 0; rr < 4; ++rr) {
      int row = rowbase + rr;
      oro[rr] = (row < mp) ? ridx[row] : -1;
    }
    float ps[4] = {0.f, 0.f, 0.f, 0.f};
#pragma unroll
    for (int ni = 0; ni < 4; ++ni)
#pragma unroll
      for (int rr = 0; rr < 4; ++rr) {
        int bb = (oro[rr] >= 0 ? oro[rr] : 0) >> 11;
        ps[rr] += fast_tanh(acc[mi][ni][rr] + qp[bb * H_ + hh[ni]]) * vv[ni];
      }
#pragma unroll
    for (int off = 1; off < 16; off <<= 1)
#pragma unroll
      for (int rr = 0; rr < 4; ++rr)
        ps[rr] += __shfl_xor(ps[rr], off, 64);
    if ((lane & 15) == 0) {
#pragma unroll
      for (int rr = 0; rr < 4; ++rr)
        if (oro[rr] >= 0) atomicAdd(&energy[oro[rr]], ps[rr]);
    }
  }
}

// ---------------------------------------------------------------- fallback GEMM (f32 keys, full M)
__global__ __launch_bounds__(256) void gemm_energy(
    const float* __restrict__ keys, const __bf16* __restrict__ wk,
    const float* __restrict__ qp, const float* __restrict__ v,
    float* __restrict__ energy) {
  __shared__ __align__(16) __bf16 As[128 * 32];
  __shared__ __align__(16) __bf16 Bs[128 * 32];

  const int tid  = threadIdx.x;
  const int w    = tid >> 6;
  const int lane = tid & 63;

  const int orig = blockIdx.x;
  const int wgid = (orig & 7) * 1024 + (orig >> 3);
  const int m0 = (wgid >> 3) * 128;
  const int n0 = (wgid & 7) * 128;

  const int wm = w >> 1, wn = w & 1;

  f32x4 acc[4][4] = {};

  int arow[2], aslot[2];
#pragma unroll
  for (int i = 0; i < 2; ++i) {
    int c = tid + i * 256;
    arow[i]  = c >> 2;
    aslot[i] = c & 3;
  }
  const float* Abase = keys + (size_t)m0 * K_;

  int brow[2], bs_src[2], bs_dst[2];
#pragma unroll
  for (int j = 0; j < 2; ++j) {
    int flat = w * 1024 + j * 512 + lane * 8;
    brow[j]   = flat >> 5;
    bs_src[j] = (((flat >> 3) & 3) ^ ((brow[j] >> 1) & 3)) * 8;
    bs_dst[j] = w * 1024 + j * 512;
  }

  float4 pre[2][2];
#pragma unroll
  for (int i = 0; i < 2; ++i) {
    const float* p = Abase + arow[i] * K_ + aslot[i] * 8;
    pre[i][0] = *(const float4*)p;
    pre[i][1] = *(const float4*)(p + 4);
  }

  for (int kt = 0; kt < 32; ++kt) {
    const int k0 = kt * 32;
#pragma unroll
    for (int i = 0; i < 2; ++i) {
      bf16x8 u;
      u[0] = (__bf16)pre[i][0].x; u[1] = (__bf16)pre[i][0].y;
      u[2] = (__bf16)pre[i][0].z; u[3] = (__bf16)pre[i][0].w;
      u[4] = (__bf16)pre[i][1].x; u[5] = (__bf16)pre[i][1].y;
      u[6] = (__bf16)pre[i][1].z; u[7] = (__bf16)pre[i][1].w;
      *(bf16x8*)(&As[swz(arow[i], aslot[i])]) = u;
    }
#pragma unroll
    for (int j = 0; j < 2; ++j)
      async16(wk + (size_t)(n0 + brow[j]) * K_ + k0 + bs_src[j], &Bs[bs_dst[j]]);
    __syncthreads();
    if (kt + 1 < 32) {
#pragma unroll
      for (int i = 0; i < 2; ++i) {
        const float* p = Abase + arow[i] * K_ + (k0 + 32) + aslot[i] * 8;
        pre[i][0] = *(const float4*)p;
        pre[i][1] = *(const float4*)(p + 4);
      }
    }
    const int g = lane >> 4;
    bf16x8 af[4], bfr[4];
#pragma unroll
    for (int mi = 0; mi < 4; ++mi) {
      int r = wm * 64 + mi * 16 + (lane & 15);
      af[mi] = *(const bf16x8*)(&As[swz(r, g)]);
    }
#pragma unroll
    for (int ni = 0; ni < 4; ++ni) {
      int r = wn * 64 + ni * 16 + (lane & 15);
      bfr[ni] = *(const bf16x8*)(&Bs[swz(r, g)]);
    }
#pragma unroll
    for (int mi = 0; mi < 4; ++mi)
#pragma unroll
      for (int ni = 0; ni < 4; ++ni)
        acc[mi][ni] = __builtin_amdgcn_mfma_f32_16x16x32_bf16(af[mi], bfr[ni], acc[mi][ni], 0, 0, 0);
    __syncthreads();
  }

  const int bb = m0 >> 11;
  float qpv[4], vv[4];
#pragma unroll
  for (int ni = 0; ni < 4; ++ni) {
    int h = n0 + wn * 64 + ni * 16 + (lane & 15);
    qpv[ni] = qp[bb * H_ + h];
    vv[ni]  = v[h];
  }
#pragma unroll
  for (int mi = 0; mi < 4; ++mi) {
    float ps[4] = {0.f, 0.f, 0.f, 0.f};
#pragma unroll
    for (int ni = 0; ni < 4; ++ni)
#pragma unroll
      for (int rr = 0; rr < 4; ++rr)
        ps[rr] += fast_tanh(acc[mi][ni][rr] + qpv[ni]) * vv[ni];
#pragma unroll
    for (int off = 1; off < 16; off <<= 1)
#pragma unroll
      for (int rr = 0; rr < 4; ++rr)
        ps[rr] += __shfl_xor(ps[rr], off, 64);
    if ((lane & 15) == 0) {
      int rowbase = m0 + wm * 64 + mi * 16 + (lane >> 4) * 4;
#pragma unroll
      for (int rr = 0; rr < 4; ++rr)
        atomicAdd(&energy[rowbase + rr], ps[rr]);
    }
  }
}

// ---------------------------------------------------------------- masked softmax
__global__ void softmax_kernel(const float* __restrict__ energy, const void* __restrict__ mask,
                               const int* __restrict__ flag, float* __restrict__ attn) {
  __shared__ float red[256];
  const int b = blockIdx.x, t = threadIdx.x;
  const int fl = flag[0];
  float e[8];
#pragma unroll
  for (int i = 0; i < 8; ++i) {
    int idx = b * S_ + i * 256 + t;
    e[i] = mask_at(mask, fl, idx) ? -INFINITY : energy[idx];
  }
  float mx = e[0];
#pragma unroll
  for (int i = 1; i < 8; ++i) mx = fmaxf(mx, e[i]);
  red[t] = mx; __syncthreads();
  for (int o = 128; o > 0; o >>= 1) { if (t < o) red[t] = fmaxf(red[t], red[t + o]); __syncthreads(); }
  mx = red[0];
  __syncthreads();
  const bool any = (mx > -INFINITY);
  float p[8]; float sum = 0.f;
#pragma unroll
  for (int i = 0; i < 8; ++i) {
    p[i] = (any && e[i] > -INFINITY) ? __expf(e[i] - mx) : 0.f;
    sum += p[i];
  }
  red[t] = sum; __syncthreads();
  for (int o = 128; o > 0; o >>= 1) { if (t < o) red[t] += red[t + o]; __syncthreads(); }
  sum = red[0];
  const float inv = (sum > 0.f) ? 1.f / sum : 0.f;
#pragma unroll
  for (int i = 0; i < 8; ++i) attn[b * S_ + i * 256 + t] = p[i] * inv;
}

// ---------------------------------------------------------------- context, gathered f32 keys
// ctx[b] += sum_j attn[ridx[j]] * keys[ridx[j]]; batch monotonic in j -> flush on change.
__global__ void context_g(const float* __restrict__ attn, const float* __restrict__ keys,
                          const int* __restrict__ misc, const int* __restrict__ ridx,
                          float* __restrict__ ctx) {
  const int mp = misc[1];
  const int j0 = blockIdx.x * 128;
  if (j0 >= mp) return;
  const int jend = (j0 + 128 < mp) ? j0 + 128 : mp;
  const int t = threadIdx.x;                 // k = 4t..4t+3
  float4 acc = {0.f, 0.f, 0.f, 0.f};
  int curb = ridx[j0] >> 11;
  for (int j = j0; j < jend; ++j) {
    const int row = ridx[j];
    const int b = row >> 11;
    if (b != curb) {
      float* cb = ctx + curb * K_ + t * 4;
      atomicAdd(cb + 0, acc.x); atomicAdd(cb + 1, acc.y);
      atomicAdd(cb + 2, acc.z); atomicAdd(cb + 3, acc.w);
      acc.x = acc.y = acc.z = acc.w = 0.f;
      curb = b;
    }
    const float a = attn[row];
    if (a != 0.f) {
      float4 kv = *(const float4*)(keys + (size_t)row * K_ + t * 4);
      acc.x += a * kv.x; acc.y += a * kv.y; acc.z += a * kv.z; acc.w += a * kv.w;
    }
  }
  float* cb = ctx + curb * K_ + t * 4;
  atomicAdd(cb + 0, acc.x); atomicAdd(cb + 1, acc.y);
  atomicAdd(cb + 2, acc.z); atomicAdd(cb + 3, acc.w);
}

// ---------------------------------------------------------------- fallback context (dense f32)
__global__ void context_kernel(const float* __restrict__ attn, const float* __restrict__ keys,
                               float* __restrict__ ctx) {
  const int b = blockIdx.y;
  const int sc = blockIdx.x;
  const int t = threadIdx.x;
  const float* kb = keys + ((size_t)b * S_ + sc * 128) * K_;
  const float* ab = attn + b * S_ + sc * 128;
  float4 acc = {0.f, 0.f, 0.f, 0.f};
  for (int s = 0; s < 128; ++s) {
    float a = ab[s];
    if (a != 0.f) {
      float4 kv = *(const float4*)(kb + (size_t)s * K_ + t * 4);
      acc.x += a * kv.x; acc.y += a * kv.y; acc.z += a * kv.z; acc.w += a * kv.w;
    }
  }
  float* cb = ctx + b * K_ + t * 4;
  atomicAdd(cb + 0, acc.x);
  atomicAdd(cb + 1, acc.y);
  atomicAdd(cb + 2, acc.z);
  atomicAdd(cb + 3, acc.w);
}

// ---------------------------------------------------------------- launch
extern "C" void kernel_launch(void* const* d_in, const int* in_sizes, int n_in,
                              void* d_out, int out_size, void* d_ws, size_t ws_size,
                              hipStream_t stream) {
  (void)in_sizes; (void)n_in; (void)out_size;
  const float* query = (const float*)d_in[0];
  const float* keys  = (const float*)d_in[1];
  const void*  mask  = d_in[2];
  const float* Wq    = (const float*)d_in[3];
  const float* Wk    = (const float*)d_in[4];
  const float* v     = (const float*)d_in[5];

  float* ctx  = (float*)d_out;             // [64][1024]
  float* attn = (float*)d_out + B_ * K_;   // [64][2048]

  char* ws = (char*)d_ws;
  float*          energy = (float*)ws;                              // 512 KiB
  float*          qp     = (float*)(ws + (512 << 10));              // 256 KiB
  unsigned short* wkb    = (unsigned short*)(ws + (768 << 10));     // 2 MiB
  int*            misc   = (int*)(ws + (768 << 10) + (2 << 20));    // 4 KiB
  int*            ridx   = (int*)(ws + (3 << 20));                  // 512 KiB

  const bool big = ws_size >= (size_t)(4 << 20);

  hipMemsetAsync(energy, 0, (size_t)M_ * 4, stream);
  hipMemsetAsync(ctx, 0, (size_t)B_ * K_ * 4, stream);
  detect_mask<<<1, 256, 0, stream>>>((const unsigned int*)mask, misc);
  convert_wk<<<(H_ * K_ / 4) / 256, 256, 0, stream>>>(Wk, wkb);
  qp_kernel<<<B_, 256, 0, stream>>>(query, Wq, qp);
  if (big) {
    mask_count<<<128, 256, 0, stream>>>(mask, misc);
    mask_scan<<<1, 64, 0, stream>>>(misc);
    mask_writeidx<<<128, 256, 0, stream>>>(mask, misc, ridx);
    gemm_energy_g<<<(M_ / 128) * (H_ / 128), 256, 0, stream>>>(
        keys, (const __bf16*)wkb, qp, v, energy, misc, ridx);
    softmax_kernel<<<B_, 256, 0, stream>>>(energy, mask, misc, attn);
    context_g<<<M_ / 128, 256, 0, stream>>>(attn, keys, misc, ridx, ctx);
  } else {
    gemm_energy<<<(M_ / 128) * (H_ / 128), 256, 0, stream>>>(
        keys, (const __bf16*)wkb, qp, v, energy);
    softmax_kernel<<<B_, 256, 0, stream>>>(energy, mask, misc, attn);
    context_kernel<<<dim3(S_ / 128, B_), 256, 0, stream>>>(attn, keys, ctx);
  }
}

// Round 11
// 347.045 us; speedup vs baseline: 2.6305x; 1.2667x over previous
//
#include <hip/hip_runtime.h>
#include <math.h>

#define B_ 64
#define S_ 2048
#define H_ 1024
#define K_ 1024
#define M_ (B_*S_)   // 131072 rows of the big GEMM

using f32x4   = __attribute__((ext_vector_type(4))) float;
using bf16x8  = __attribute__((ext_vector_type(8))) __bf16;

__device__ __forceinline__ unsigned short f2b(float f) {
  unsigned int u = __float_as_uint(f);
  u += 0x7fffu + ((u >> 16) & 1u);   // RNE
  return (unsigned short)(u >> 16);
}

// tanh(x) = (e^2x - 1)/(e^2x + 1); clamp so t stays finite (tanh saturated anyway)
__device__ __forceinline__ float fast_tanh(float x) {
  float xc = fminf(fmaxf(x, -15.f), 15.f);
  float t = __expf(2.f * xc);
  return (t - 1.f) * __builtin_amdgcn_rcpf(t + 1.f);
}

typedef __attribute__((address_space(1))) void gvoid_t;
typedef __attribute__((address_space(3))) void lvoid_t;

__device__ __forceinline__ void async16(const void* g, void* l) {
  __builtin_amdgcn_global_load_lds((gvoid_t*)g, (lvoid_t*)l, 16, 0, 0);
}

// bf16 B tile [128][32]: XOR-swizzled element offset for (row r, 16B-slot sl)
__device__ __forceinline__ int swz(int r, int sl) {
  return r * 32 + ((sl ^ ((r >> 1) & 3)) << 3);
}

// f32 A tile [128 rows][32 f32] = 8 chunks of 16B per row; chunk' = chunk ^ (r&7)
__device__ __forceinline__ int swzf(int r, int chunk) {
  return r * 32 + ((chunk ^ (r & 7)) << 2);   // float elements
}

// mask decode shared by all mask readers
__device__ __forceinline__ bool mask_at(const void* mask, int fl, int idx) {
  if (fl == 1)      return ((const unsigned char*)mask)[idx] != 0;
  else if (fl == 2) return ((const float*)mask)[idx] != 0.f;
  else              return ((const int*)mask)[idx] != 0;
}

// misc layout (ints): [0]=flag [1]=Mp [2]=Mpr(128-rounded)
//                     [16..144)=blocksum  [144..272]=blockoff (272 = Mp sentinel)

// ---------------------------------------------------------------- mask dtype
__global__ void detect_mask(const unsigned int* __restrict__ m, int* __restrict__ misc) {
  __shared__ int red[256];
  int t = threadIdx.x;
  int f = 0;
  for (int i = 0; i < 32; ++i) {
    unsigned int w = m[t * 32 + i];
    if (w > 1u) f |= 1;
    if (w != 0u && w != 0x3f800000u) f |= 2;
  }
  red[t] = f;
  __syncthreads();
  for (int o = 128; o > 0; o >>= 1) { if (t < o) red[t] |= red[t + o]; __syncthreads(); }
  if (t == 0) {
    int g = red[0];
    misc[0] = ((g & 1) == 0) ? 0 : (((g & 2) == 0) ? 2 : 1);
  }
}

// ---------------------------------------------------------------- compaction scans
__global__ void mask_count(const void* __restrict__ mask, int* __restrict__ misc) {
  __shared__ int red[256];
  const int fl = misc[0];
  const int t = threadIdx.x, blk = blockIdx.x;
  int cnt = 0;
#pragma unroll
  for (int i = 0; i < 4; ++i)
    cnt += mask_at(mask, fl, blk * 1024 + t * 4 + i) ? 0 : 1;
  red[t] = cnt; __syncthreads();
  for (int o = 128; o > 0; o >>= 1) { if (t < o) red[t] += red[t + o]; __syncthreads(); }
  if (t == 0) misc[16 + blk] = red[0];
}

__global__ void mask_scan(int* __restrict__ misc) {
  if (threadIdx.x == 0) {
    int acc = 0;
    for (int i = 0; i < 128; ++i) { misc[144 + i] = acc; acc += misc[16 + i]; }
    misc[144 + 128] = acc;    // sentinel: end of batch 63
    misc[1] = acc;
    misc[2] = (acc + 127) & ~127;
  }
}

__global__ void mask_writeidx(const void* __restrict__ mask, const int* __restrict__ misc,
                              int* __restrict__ ridx) {
  __shared__ int sc[256];
  const int fl = misc[0];
  const int t = threadIdx.x, blk = blockIdx.x;
  int um[4]; int cnt = 0;
#pragma unroll
  for (int i = 0; i < 4; ++i) {
    um[i] = mask_at(mask, fl, blk * 1024 + t * 4 + i) ? 0 : 1;
    cnt += um[i];
  }
  sc[t] = cnt; __syncthreads();
  for (int o = 1; o < 256; o <<= 1) {
    int v = (t >= o) ? sc[t - o] : 0;
    __syncthreads();
    sc[t] += v;
    __syncthreads();
  }
  int base = misc[144 + blk] + sc[t] - cnt;   // exclusive prefix
#pragma unroll
  for (int i = 0; i < 4; ++i)
    if (um[i]) ridx[base++] = blk * 1024 + t * 4 + i;
}

// ---------------------------------------------------------------- Wk -> bf16
__global__ void convert_wk(const float* __restrict__ src, unsigned short* __restrict__ dst) {
  int i = blockIdx.x * blockDim.x + threadIdx.x;
  float4 v = ((const float4*)src)[i];
  ushort4 o;
  o.x = f2b(v.x); o.y = f2b(v.y); o.z = f2b(v.z); o.w = f2b(v.w);
  *(ushort4*)(dst + (size_t)i * 4) = o;
}

// ---------------------------------------------------------------- qp = query @ Wq.T (widened)
__global__ void qp_kernel(const float* __restrict__ query, const float* __restrict__ Wq,
                          float* __restrict__ qp) {
  __shared__ float qs[1024];
  const int b = blockIdx.y, q4b = blockIdx.x, t = threadIdx.x;
  ((float4*)qs)[t] = ((const float4*)(query + b * 1024))[t];
  __syncthreads();
  const int h = q4b * 256 + t;
  const float4* wr = (const float4*)(Wq + (size_t)h * 1024);
  float s = 0.f;
#pragma unroll 4
  for (int q4 = 0; q4 < 256; ++q4) {
    float4 w = wr[q4];
    float4 q = ((const float4*)qs)[q4];
    s += w.x * q.x + w.y * q.y + w.z * q.z + w.w * q.w;
  }
  qp[b * 1024 + h] = s;
}

// ---------------------------------------------------------------- GEMM+energy, gather f32 A
// m97 structure; A gathered directly from original f32 keys via per-lane
// global_load_lds sources (ridx); A staged f32 swizzled, cvt after ds_read.
__global__ __launch_bounds__(256, 4) void gemm_energy_g(
    const float* __restrict__ keys,          // [M_][1024] f32 (original)
    const __bf16* __restrict__ wk,           // [1024][1024] bf16 Wk
    const float* __restrict__ qp,            // [64][1024]
    const float* __restrict__ v,             // [1024]
    float* __restrict__ energy,              // [M_] (original row ids)
    const int* __restrict__ misc,
    const int* __restrict__ ridx) {
  __shared__ __align__(16) float  Asf[128 * 32];   // 16 KB
  __shared__ __align__(16) __bf16 Bs[128 * 32];    //  8 KB

  const int tid  = threadIdx.x;
  const int w    = tid >> 6;
  const int lane = tid & 63;

  const int orig = blockIdx.x;                   // 0..8191
  const int x = orig & 7, j = orig >> 3;
  const int m0 = (x + 8 * (j >> 3)) * 128;
  const int n0 = (j & 7) * 128;

  const int mpr = misc[2];
  if (m0 >= mpr) return;
  const int mp = misc[1];

  const int wm = w >> 1, wn = w & 1;

  f32x4 acc[4][4] = {};

  const float* asrc[4]; int adst[4];
#pragma unroll
  for (int i = 0; i < 4; ++i) {
    int c = tid + i * 256;
    int r = c >> 3, cl = c & 7;
    int row = m0 + r;
    int oro = (row < mp) ? ridx[row] : ridx[mp - 1];   // clamp: pads discarded later
    asrc[i] = keys + (size_t)oro * K_ + ((cl ^ (r & 7)) << 2);
    adst[i] = (i * 256 + w * 64) * 4;
  }
  const __bf16* bsrc[2]; int bdst[2];
#pragma unroll
  for (int jj = 0; jj < 2; ++jj) {
    int c = tid + jj * 256;
    int r = c >> 2;
    int soff = (((c & 3) ^ ((r >> 1) & 3)) << 3);
    bsrc[jj] = wk + (size_t)(n0 + r) * K_ + soff;
    bdst[jj] = (jj * 256 + w * 64) * 8;
  }

  for (int kt = 0; kt < 32; ++kt) {
    const int k0 = kt * 32;
#pragma unroll
    for (int i = 0; i < 4; ++i)
      async16(asrc[i] + k0, &Asf[adst[i]]);
#pragma unroll
    for (int jj = 0; jj < 2; ++jj)
      async16(bsrc[jj] + k0, &Bs[bdst[jj]]);
    __syncthreads();
    const int g = lane >> 4;
    bf16x8 af[4], bfr[4];
#pragma unroll
    for (int mi = 0; mi < 4; ++mi) {
      int r = wm * 64 + mi * 16 + (lane & 15);
      f32x4 lo = *(const f32x4*)(&Asf[swzf(r, 2 * g)]);
      f32x4 hi = *(const f32x4*)(&Asf[swzf(r, 2 * g + 1)]);
      bf16x8 u;
      u[0] = (__bf16)lo[0]; u[1] = (__bf16)lo[1]; u[2] = (__bf16)lo[2]; u[3] = (__bf16)lo[3];
      u[4] = (__bf16)hi[0]; u[5] = (__bf16)hi[1]; u[6] = (__bf16)hi[2]; u[7] = (__bf16)hi[3];
      af[mi] = u;
    }
#pragma unroll
    for (int ni = 0; ni < 4; ++ni) {
      int r = wn * 64 + ni * 16 + (lane & 15);
      bfr[ni] = *(const bf16x8*)(&Bs[swz(r, g)]);
    }
#pragma unroll
    for (int mi = 0; mi < 4; ++mi)
#pragma unroll
      for (int ni = 0; ni < 4; ++ni)
        acc[mi][ni] = __builtin_amdgcn_mfma_f32_16x16x32_bf16(af[mi], bfr[ni], acc[mi][ni], 0, 0, 0);
    __syncthreads();
  }

  // epilogue with ridx indirection
  float vv[4]; int hh[4];
#pragma unroll
  for (int ni = 0; ni < 4; ++ni) {
    hh[ni] = n0 + wn * 64 + ni * 16 + (lane & 15);
    vv[ni] = v[hh[ni]];
  }
#pragma unroll
  for (int mi = 0; mi < 4; ++mi) {
    const int rowbase = m0 + wm * 64 + mi * 16 + (lane >> 4) * 4;
    int oro[4];
#pragma unroll
    for (int rr = 0; rr < 4; ++rr) {
      int row = rowbase + rr;
      oro[rr] = (row < mp) ? ridx[row] : -1;
    }
    float ps[4] = {0.f, 0.f, 0.f, 0.f};
#pragma unroll
    for (int ni = 0; ni < 4; ++ni)
#pragma unroll
      for (int rr = 0; rr < 4; ++rr) {
        int bb = (oro[rr] >= 0 ? oro[rr] : 0) >> 11;
        ps[rr] += fast_tanh(acc[mi][ni][rr] + qp[bb * H_ + hh[ni]]) * vv[ni];
      }
#pragma unroll
    for (int off = 1; off < 16; off <<= 1)
#pragma unroll
      for (int rr = 0; rr < 4; ++rr)
        ps[rr] += __shfl_xor(ps[rr], off, 64);
    if ((lane & 15) == 0) {
#pragma unroll
      for (int rr = 0; rr < 4; ++rr)
        if (oro[rr] >= 0) atomicAdd(&energy[oro[rr]], ps[rr]);
    }
  }
}

// ---------------------------------------------------------------- fallback GEMM (f32 keys, full M)
__global__ __launch_bounds__(256) void gemm_energy(
    const float* __restrict__ keys, const __bf16* __restrict__ wk,
    const float* __restrict__ qp, const float* __restrict__ v,
    float* __restrict__ energy) {
  __shared__ __align__(16) __bf16 As[128 * 32];
  __shared__ __align__(16) __bf16 Bs[128 * 32];

  const int tid  = threadIdx.x;
  const int w    = tid >> 6;
  const int lane = tid & 63;

  const int orig = blockIdx.x;
  const int wgid = (orig & 7) * 1024 + (orig >> 3);
  const int m0 = (wgid >> 3) * 128;
  const int n0 = (wgid & 7) * 128;

  const int wm = w >> 1, wn = w & 1;

  f32x4 acc[4][4] = {};

  int arow[2], aslot[2];
#pragma unroll
  for (int i = 0; i < 2; ++i) {
    int c = tid + i * 256;
    arow[i]  = c >> 2;
    aslot[i] = c & 3;
  }
  const float* Abase = keys + (size_t)m0 * K_;

  int brow[2], bs_src[2], bs_dst[2];
#pragma unroll
  for (int j = 0; j < 2; ++j) {
    int flat = w * 1024 + j * 512 + lane * 8;
    brow[j]   = flat >> 5;
    bs_src[j] = (((flat >> 3) & 3) ^ ((brow[j] >> 1) & 3)) * 8;
    bs_dst[j] = w * 1024 + j * 512;
  }

  float4 pre[2][2];
#pragma unroll
  for (int i = 0; i < 2; ++i) {
    const float* p = Abase + arow[i] * K_ + aslot[i] * 8;
    pre[i][0] = *(const float4*)p;
    pre[i][1] = *(const float4*)(p + 4);
  }

  for (int kt = 0; kt < 32; ++kt) {
    const int k0 = kt * 32;
#pragma unroll
    for (int i = 0; i < 2; ++i) {
      bf16x8 u;
      u[0] = (__bf16)pre[i][0].x; u[1] = (__bf16)pre[i][0].y;
      u[2] = (__bf16)pre[i][0].z; u[3] = (__bf16)pre[i][0].w;
      u[4] = (__bf16)pre[i][1].x; u[5] = (__bf16)pre[i][1].y;
      u[6] = (__bf16)pre[i][1].z; u[7] = (__bf16)pre[i][1].w;
      *(bf16x8*)(&As[swz(arow[i], aslot[i])]) = u;
    }
#pragma unroll
    for (int j = 0; j < 2; ++j)
      async16(wk + (size_t)(n0 + brow[j]) * K_ + k0 + bs_src[j], &Bs[bs_dst[j]]);
    __syncthreads();
    if (kt + 1 < 32) {
#pragma unroll
      for (int i = 0; i < 2; ++i) {
        const float* p = Abase + arow[i] * K_ + (k0 + 32) + aslot[i] * 8;
        pre[i][0] = *(const float4*)p;
        pre[i][1] = *(const float4*)(p + 4);
      }
    }
    const int g = lane >> 4;
    bf16x8 af[4], bfr[4];
#pragma unroll
    for (int mi = 0; mi < 4; ++mi) {
      int r = wm * 64 + mi * 16 + (lane & 15);
      af[mi] = *(const bf16x8*)(&As[swz(r, g)]);
    }
#pragma unroll
    for (int ni = 0; ni < 4; ++ni) {
      int r = wn * 64 + ni * 16 + (lane & 15);
      bfr[ni] = *(const bf16x8*)(&Bs[swz(r, g)]);
    }
#pragma unroll
    for (int mi = 0; mi < 4; ++mi)
#pragma unroll
      for (int ni = 0; ni < 4; ++ni)
        acc[mi][ni] = __builtin_amdgcn_mfma_f32_16x16x32_bf16(af[mi], bfr[ni], acc[mi][ni], 0, 0, 0);
    __syncthreads();
  }

  const int bb = m0 >> 11;
  float qpv[4], vv[4];
#pragma unroll
  for (int ni = 0; ni < 4; ++ni) {
    int h = n0 + wn * 64 + ni * 16 + (lane & 15);
    qpv[ni] = qp[bb * H_ + h];
    vv[ni]  = v[h];
  }
#pragma unroll
  for (int mi = 0; mi < 4; ++mi) {
    float ps[4] = {0.f, 0.f, 0.f, 0.f};
#pragma unroll
    for (int ni = 0; ni < 4; ++ni)
#pragma unroll
      for (int rr = 0; rr < 4; ++rr)
        ps[rr] += fast_tanh(acc[mi][ni][rr] + qpv[ni]) * vv[ni];
#pragma unroll
    for (int off = 1; off < 16; off <<= 1)
#pragma unroll
      for (int rr = 0; rr < 4; ++rr)
        ps[rr] += __shfl_xor(ps[rr], off, 64);
    if ((lane & 15) == 0) {
      int rowbase = m0 + wm * 64 + mi * 16 + (lane >> 4) * 4;
#pragma unroll
      for (int rr = 0; rr < 4; ++rr)
        atomicAdd(&energy[rowbase + rr], ps[rr]);
    }
  }
}

// ---------------------------------------------------------------- masked softmax
__global__ void softmax_kernel(const float* __restrict__ energy, const void* __restrict__ mask,
                               const int* __restrict__ flag, float* __restrict__ attn) {
  __shared__ float red[256];
  const int b = blockIdx.x, t = threadIdx.x;
  const int fl = flag[0];
  float e[8];
#pragma unroll
  for (int i = 0; i < 8; ++i) {
    int idx = b * S_ + i * 256 + t;
    e[i] = mask_at(mask, fl, idx) ? -INFINITY : energy[idx];
  }
  float mx = e[0];
#pragma unroll
  for (int i = 1; i < 8; ++i) mx = fmaxf(mx, e[i]);
  red[t] = mx; __syncthreads();
  for (int o = 128; o > 0; o >>= 1) { if (t < o) red[t] = fmaxf(red[t], red[t + o]); __syncthreads(); }
  mx = red[0];
  __syncthreads();
  const bool any = (mx > -INFINITY);
  float p[8]; float sum = 0.f;
#pragma unroll
  for (int i = 0; i < 8; ++i) {
    p[i] = (any && e[i] > -INFINITY) ? __expf(e[i] - mx) : 0.f;
    sum += p[i];
  }
  red[t] = sum; __syncthreads();
  for (int o = 128; o > 0; o >>= 1) { if (t < o) red[t] += red[t + o]; __syncthreads(); }
  sum = red[0];
  const float inv = (sum > 0.f) ? 1.f / sum : 0.f;
#pragma unroll
  for (int i = 0; i < 8; ++i) attn[b * S_ + i * 256 + t] = p[i] * inv;
}

// ---------------------------------------------------------------- context, per-(batch,chunk)
// Each block handles one batch's compact sub-range -> no batch-flush branch in
// the loop, clean unroll, loads independent. blocks = 64 batches x 32 chunks.
__global__ void context_gb(const float* __restrict__ attn, const float* __restrict__ keys,
                           const int* __restrict__ misc, const int* __restrict__ ridx,
                           float* __restrict__ ctx) {
  const int b = blockIdx.y, chunk = blockIdx.x;
  const int jb = misc[144 + 2 * b];
  const int je = misc[144 + 2 * b + 2];     // sentinel at [144+128] covers b=63
  const int j0 = jb + chunk * 64;
  if (j0 >= je) return;
  const int j1 = (j0 + 64 < je) ? j0 + 64 : je;
  const int t = threadIdx.x;                 // k = 4t..4t+3
  float4 acc = {0.f, 0.f, 0.f, 0.f};
#pragma unroll 4
  for (int j = j0; j < j1; ++j) {
    const int row = ridx[j];
    const float a = attn[row];
    float4 kv = *(const float4*)(keys + (size_t)row * K_ + t * 4);
    acc.x += a * kv.x; acc.y += a * kv.y; acc.z += a * kv.z; acc.w += a * kv.w;
  }
  float* cb = ctx + b * K_ + t * 4;
  atomicAdd(cb + 0, acc.x); atomicAdd(cb + 1, acc.y);
  atomicAdd(cb + 2, acc.z); atomicAdd(cb + 3, acc.w);
}

// ---------------------------------------------------------------- fallback context (dense f32)
__global__ void context_kernel(const float* __restrict__ attn, const float* __restrict__ keys,
                               float* __restrict__ ctx) {
  const int b = blockIdx.y;
  const int sc = blockIdx.x;
  const int t = threadIdx.x;
  const float* kb = keys + ((size_t)b * S_ + sc * 128) * K_;
  const float* ab = attn + b * S_ + sc * 128;
  float4 acc = {0.f, 0.f, 0.f, 0.f};
  for (int s = 0; s < 128; ++s) {
    float a = ab[s];
    if (a != 0.f) {
      float4 kv = *(const float4*)(kb + (size_t)s * K_ + t * 4);
      acc.x += a * kv.x; acc.y += a * kv.y; acc.z += a * kv.z; acc.w += a * kv.w;
    }
  }
  float* cb = ctx + b * K_ + t * 4;
  atomicAdd(cb + 0, acc.x);
  atomicAdd(cb + 1, acc.y);
  atomicAdd(cb + 2, acc.z);
  atomicAdd(cb + 3, acc.w);
}

// ---------------------------------------------------------------- launch
extern "C" void kernel_launch(void* const* d_in, const int* in_sizes, int n_in,
                              void* d_out, int out_size, void* d_ws, size_t ws_size,
                              hipStream_t stream) {
  (void)in_sizes; (void)n_in; (void)out_size;
  const float* query = (const float*)d_in[0];
  const float* keys  = (const float*)d_in[1];
  const void*  mask  = d_in[2];
  const float* Wq    = (const float*)d_in[3];
  const float* Wk    = (const float*)d_in[4];
  const float* v     = (const float*)d_in[5];

  float* ctx  = (float*)d_out;             // [64][1024]
  float* attn = (float*)d_out + B_ * K_;   // [64][2048]

  char* ws = (char*)d_ws;
  float*          energy = (float*)ws;                              // 512 KiB
  float*          qp     = (float*)(ws + (512 << 10));              // 256 KiB
  unsigned short* wkb    = (unsigned short*)(ws + (768 << 10));     // 2 MiB
  int*            misc   = (int*)(ws + (768 << 10) + (2 << 20));    // 4 KiB
  int*            ridx   = (int*)(ws + (3 << 20));                  // 512 KiB

  const bool big = ws_size >= (size_t)(4 << 20);

  hipMemsetAsync(energy, 0, (size_t)M_ * 4, stream);
  hipMemsetAsync(ctx, 0, (size_t)B_ * K_ * 4, stream);
  detect_mask<<<1, 256, 0, stream>>>((const unsigned int*)mask, misc);
  convert_wk<<<(H_ * K_ / 4) / 256, 256, 0, stream>>>(Wk, wkb);
  qp_kernel<<<dim3(4, B_), 256, 0, stream>>>(query, Wq, qp);
  if (big) {
    mask_count<<<128, 256, 0, stream>>>(mask, misc);
    mask_scan<<<1, 64, 0, stream>>>(misc);
    mask_writeidx<<<128, 256, 0, stream>>>(mask, misc, ridx);
    gemm_energy_g<<<(M_ / 128) * (H_ / 128), 256, 0, stream>>>(
        keys, (const __bf16*)wkb, qp, v, energy, misc, ridx);
    softmax_kernel<<<B_, 256, 0, stream>>>(energy, mask, misc, attn);
    context_gb<<<dim3(32, B_), 256, 0, stream>>>(attn, keys, misc, ridx, ctx);
  } else {
    gemm_energy<<<(M_ / 128) * (H_ / 128), 256, 0, stream>>>(
        keys, (const __bf16*)wkb, qp, v, energy);
    softmax_kernel<<<B_, 256, 0, stream>>>(energy, mask, misc, attn);
    context_kernel<<<dim3(S_ / 128, B_), 256, 0, stream>>>(attn, keys, ctx);
  }
}

// Round 12
// 334.460 us; speedup vs baseline: 2.7295x; 1.0376x over previous
//
#include <hip/hip_runtime.h>
#include <math.h>

#define B_ 64
#define S_ 2048
#define H_ 1024
#define K_ 1024
#define M_ (B_*S_)   // 131072 rows of the big GEMM

using f32x4   = __attribute__((ext_vector_type(4))) float;
using bf16x8  = __attribute__((ext_vector_type(8))) __bf16;

__device__ __forceinline__ unsigned short f2b(float f) {
  unsigned int u = __float_as_uint(f);
  u += 0x7fffu + ((u >> 16) & 1u);   // RNE
  return (unsigned short)(u >> 16);
}

// tanh(x) = (e^2x - 1)/(e^2x + 1); clamp so t stays finite (tanh saturated anyway)
__device__ __forceinline__ float fast_tanh(float x) {
  float xc = fminf(fmaxf(x, -15.f), 15.f);
  float t = __expf(2.f * xc);
  return (t - 1.f) * __builtin_amdgcn_rcpf(t + 1.f);
}

typedef __attribute__((address_space(1))) void gvoid_t;
typedef __attribute__((address_space(3))) void lvoid_t;

__device__ __forceinline__ void async16(const void* g, void* l) {
  __builtin_amdgcn_global_load_lds((gvoid_t*)g, (lvoid_t*)l, 16, 0, 0);
}

// ---- BK=64 tile swizzles (both-sides: source column pre-permuted, read XOR'd)
// A f32 [128][64]: 16 chunks of 16B per row; chunk' = chunk ^ ((r&7)<<1)
// (bit0 preserved -> 16B pairs stay adjacent; 2-way bank alias = free)
__device__ __forceinline__ int swzf64(int r, int chunk) {
  return r * 64 + ((chunk ^ ((r & 7) << 1)) << 2);   // f32 elements
}
// B bf16 [128][64]: 8 slots of 16B per row; slot' = sl ^ (r&7)
__device__ __forceinline__ int swzb64(int r, int sl) {
  return r * 64 + ((sl ^ (r & 7)) << 3);             // bf16 elements
}
// legacy 32-wide swizzle for the fallback kernel
__device__ __forceinline__ int swz(int r, int sl) {
  return r * 32 + ((sl ^ ((r >> 1) & 3)) << 3);
}

// mask decode shared by all mask readers
__device__ __forceinline__ bool mask_at(const void* mask, int fl, int idx) {
  if (fl == 1)      return ((const unsigned char*)mask)[idx] != 0;
  else if (fl == 2) return ((const float*)mask)[idx] != 0.f;
  else              return ((const int*)mask)[idx] != 0;
}

// misc layout (ints): [0]=flag [1]=Mp [2]=Mpr(128-rounded)
//                     [16..144)=blocksum  [144..272]=blockoff (272 = Mp sentinel)

// ---------------------------------------------------------------- mask dtype
__global__ void detect_mask(const unsigned int* __restrict__ m, int* __restrict__ misc) {
  __shared__ int red[256];
  int t = threadIdx.x;
  int f = 0;
  for (int i = 0; i < 32; ++i) {
    unsigned int w = m[t * 32 + i];
    if (w > 1u) f |= 1;
    if (w != 0u && w != 0x3f800000u) f |= 2;
  }
  red[t] = f;
  __syncthreads();
  for (int o = 128; o > 0; o >>= 1) { if (t < o) red[t] |= red[t + o]; __syncthreads(); }
  if (t == 0) {
    int g = red[0];
    misc[0] = ((g & 1) == 0) ? 0 : (((g & 2) == 0) ? 2 : 1);
  }
}

// ---------------------------------------------------------------- compaction scans
__global__ void mask_count(const void* __restrict__ mask, int* __restrict__ misc) {
  __shared__ int red[256];
  const int fl = misc[0];
  const int t = threadIdx.x, blk = blockIdx.x;
  int cnt = 0;
#pragma unroll
  for (int i = 0; i < 4; ++i)
    cnt += mask_at(mask, fl, blk * 1024 + t * 4 + i) ? 0 : 1;
  red[t] = cnt; __syncthreads();
  for (int o = 128; o > 0; o >>= 1) { if (t < o) red[t] += red[t + o]; __syncthreads(); }
  if (t == 0) misc[16 + blk] = red[0];
}

__global__ void mask_scan(int* __restrict__ misc) {
  if (threadIdx.x == 0) {
    int acc = 0;
    for (int i = 0; i < 128; ++i) { misc[144 + i] = acc; acc += misc[16 + i]; }
    misc[144 + 128] = acc;    // sentinel: end of batch 63
    misc[1] = acc;
    misc[2] = (acc + 127) & ~127;
  }
}

__global__ void mask_writeidx(const void* __restrict__ mask, const int* __restrict__ misc,
                              int* __restrict__ ridx) {
  __shared__ int sc[256];
  const int fl = misc[0];
  const int t = threadIdx.x, blk = blockIdx.x;
  int um[4]; int cnt = 0;
#pragma unroll
  for (int i = 0; i < 4; ++i) {
    um[i] = mask_at(mask, fl, blk * 1024 + t * 4 + i) ? 0 : 1;
    cnt += um[i];
  }
  sc[t] = cnt; __syncthreads();
  for (int o = 1; o < 256; o <<= 1) {
    int v = (t >= o) ? sc[t - o] : 0;
    __syncthreads();
    sc[t] += v;
    __syncthreads();
  }
  int base = misc[144 + blk] + sc[t] - cnt;   // exclusive prefix
#pragma unroll
  for (int i = 0; i < 4; ++i)
    if (um[i]) ridx[base++] = blk * 1024 + t * 4 + i;
}

// ---------------------------------------------------------------- Wk -> bf16
__global__ void convert_wk(const float* __restrict__ src, unsigned short* __restrict__ dst) {
  int i = blockIdx.x * blockDim.x + threadIdx.x;
  float4 v = ((const float4*)src)[i];
  ushort4 o;
  o.x = f2b(v.x); o.y = f2b(v.y); o.z = f2b(v.z); o.w = f2b(v.w);
  *(ushort4*)(dst + (size_t)i * 4) = o;
}

// ---------------------------------------------------------------- qp = query @ Wq.T
__global__ void qp_kernel(const float* __restrict__ query, const float* __restrict__ Wq,
                          float* __restrict__ qp) {
  __shared__ float qs[1024];
  const int b = blockIdx.y, q4b = blockIdx.x, t = threadIdx.x;
  ((float4*)qs)[t] = ((const float4*)(query + b * 1024))[t];
  __syncthreads();
  const int h = q4b * 256 + t;
  const float4* wr = (const float4*)(Wq + (size_t)h * 1024);
  float s = 0.f;
#pragma unroll 4
  for (int q4 = 0; q4 < 256; ++q4) {
    float4 w = wr[q4];
    float4 q = ((const float4*)qs)[q4];
    s += w.x * q.x + w.y * q.y + w.z * q.z + w.w * q.w;
  }
  qp[b * 1024 + h] = s;
}

// ---------------------------------------------------------------- GEMM+energy, gather f32 A, BK=64
// m97 gather structure, BK widened 32->64: barrier-drain events halve (16 steps),
// 32 MFMA/wave per step. No A staging regs (pure global_load_lds), so unlike R6
// the VGPR cost is flat. LDS 48KB -> 3 blocks/CU.
__global__ __launch_bounds__(256, 3) void gemm_energy_g(
    const float* __restrict__ keys,          // [M_][1024] f32 (original)
    const __bf16* __restrict__ wk,           // [1024][1024] bf16 Wk
    const float* __restrict__ qp,            // [64][1024]
    const float* __restrict__ v,             // [1024]
    float* __restrict__ energy,              // [M_] (original row ids)
    const int* __restrict__ misc,
    const int* __restrict__ ridx) {
  __shared__ __align__(16) float  Asf[128 * 64];   // 32 KB
  __shared__ __align__(16) __bf16 Bs[128 * 64];    // 16 KB

  const int tid  = threadIdx.x;
  const int w    = tid >> 6;
  const int lane = tid & 63;

  // XCD mapping (R9-proven): all 8 n-tiles of an m-tile on one XCD; working
  // m-tiles spread over all XCDs regardless of compact count.
  const int orig = blockIdx.x;                   // 0..8191
  const int x = orig & 7, j = orig >> 3;
  const int m0 = (x + 8 * (j >> 3)) * 128;
  const int n0 = (j & 7) * 128;

  const int mpr = misc[2];
  const int mp  = misc[1];
  if (m0 >= mpr || mp == 0) return;

  const int wm = w >> 1, wn = w & 1;

  f32x4 acc[4][4] = {};

  // A staging: [128][64] f32 = 2048 chunks of 16B; this thread owns 8.
  // 32-bit element offsets into keys (gathered row via ridx, source-swizzled col).
  int aoff[8];
#pragma unroll
  for (int i = 0; i < 8; ++i) {
    int c = tid + i * 256;
    int r = c >> 4, chunk = c & 15;
    int row = m0 + r;
    int oro = (row < mp) ? ridx[row] : ridx[mp - 1];   // clamp: pads discarded later
    aoff[i] = oro * K_ + ((chunk ^ ((r & 7) << 1)) << 2);
  }
  // B staging: [128][64] bf16 = 1024 chunks of 16B; this thread owns 4.
  int boff[4];
#pragma unroll
  for (int jj = 0; jj < 4; ++jj) {
    int c = tid + jj * 256;
    int r = c >> 3, sl = c & 7;
    boff[jj] = (n0 + r) * K_ + ((sl ^ (r & 7)) << 3);
  }

  for (int kt = 0; kt < 16; ++kt) {
    const int k0 = kt * 64;
#pragma unroll
    for (int i = 0; i < 8; ++i)
      async16(keys + (size_t)aoff[i] + k0, &Asf[(i * 256 + w * 64) * 4]);
#pragma unroll
    for (int jj = 0; jj < 4; ++jj)
      async16(wk + (size_t)boff[jj] + k0, &Bs[(jj * 256 + w * 64) * 8]);
    __syncthreads();
    const int g = lane >> 4;
#pragma unroll
    for (int ks = 0; ks < 2; ++ks) {
      bf16x8 af[4], bfr[4];
#pragma unroll
      for (int mi = 0; mi < 4; ++mi) {
        int r = wm * 64 + mi * 16 + (lane & 15);
        int e = swzf64(r, ks * 8 + g * 2);
        f32x4 lo = *(const f32x4*)(&Asf[e]);
        f32x4 hi = *(const f32x4*)(&Asf[e + 4]);
        bf16x8 u;
        u[0] = (__bf16)lo[0]; u[1] = (__bf16)lo[1]; u[2] = (__bf16)lo[2]; u[3] = (__bf16)lo[3];
        u[4] = (__bf16)hi[0]; u[5] = (__bf16)hi[1]; u[6] = (__bf16)hi[2]; u[7] = (__bf16)hi[3];
        af[mi] = u;
      }
#pragma unroll
      for (int ni = 0; ni < 4; ++ni) {
        int r = wn * 64 + ni * 16 + (lane & 15);
        bfr[ni] = *(const bf16x8*)(&Bs[swzb64(r, ks * 4 + g)]);
      }
#pragma unroll
      for (int mi = 0; mi < 4; ++mi)
#pragma unroll
        for (int ni = 0; ni < 4; ++ni)
          acc[mi][ni] = __builtin_amdgcn_mfma_f32_16x16x32_bf16(af[mi], bfr[ni], acc[mi][ni], 0, 0, 0);
    }
    __syncthreads();
  }

  // epilogue with ridx indirection
  float vv[4]; int hh[4];
#pragma unroll
  for (int ni = 0; ni < 4; ++ni) {
    hh[ni] = n0 + wn * 64 + ni * 16 + (lane & 15);
    vv[ni] = v[hh[ni]];
  }
#pragma unroll
  for (int mi = 0; mi < 4; ++mi) {
    const int rowbase = m0 + wm * 64 + mi * 16 + (lane >> 4) * 4;
    int oro[4];
#pragma unroll
    for (int rr = 0; rr < 4; ++rr) {
      int row = rowbase + rr;
      oro[rr] = (row < mp) ? ridx[row] : -1;
    }
    float ps[4] = {0.f, 0.f, 0.f, 0.f};
#pragma unroll
    for (int ni = 0; ni < 4; ++ni)
#pragma unroll
      for (int rr = 0; rr < 4; ++rr) {
        int bb = (oro[rr] >= 0 ? oro[rr] : 0) >> 11;
        ps[rr] += fast_tanh(acc[mi][ni][rr] + qp[bb * H_ + hh[ni]]) * vv[ni];
      }
#pragma unroll
    for (int off = 1; off < 16; off <<= 1)
#pragma unroll
      for (int rr = 0; rr < 4; ++rr)
        ps[rr] += __shfl_xor(ps[rr], off, 64);
    if ((lane & 15) == 0) {
#pragma unroll
      for (int rr = 0; rr < 4; ++rr)
        if (oro[rr] >= 0) atomicAdd(&energy[oro[rr]], ps[rr]);
    }
  }
}

// ---------------------------------------------------------------- fallback GEMM (f32 keys, full M)
__global__ __launch_bounds__(256) void gemm_energy(
    const float* __restrict__ keys, const __bf16* __restrict__ wk,
    const float* __restrict__ qp, const float* __restrict__ v,
    float* __restrict__ energy) {
  __shared__ __align__(16) __bf16 As[128 * 32];
  __shared__ __align__(16) __bf16 Bs[128 * 32];

  const int tid  = threadIdx.x;
  const int w    = tid >> 6;
  const int lane = tid & 63;

  const int orig = blockIdx.x;
  const int wgid = (orig & 7) * 1024 + (orig >> 3);
  const int m0 = (wgid >> 3) * 128;
  const int n0 = (wgid & 7) * 128;

  const int wm = w >> 1, wn = w & 1;

  f32x4 acc[4][4] = {};

  int arow[2], aslot[2];
#pragma unroll
  for (int i = 0; i < 2; ++i) {
    int c = tid + i * 256;
    arow[i]  = c >> 2;
    aslot[i] = c & 3;
  }
  const float* Abase = keys + (size_t)m0 * K_;

  int brow[2], bs_src[2], bs_dst[2];
#pragma unroll
  for (int j = 0; j < 2; ++j) {
    int flat = w * 1024 + j * 512 + lane * 8;
    brow[j]   = flat >> 5;
    bs_src[j] = (((flat >> 3) & 3) ^ ((brow[j] >> 1) & 3)) * 8;
    bs_dst[j] = w * 1024 + j * 512;
  }

  float4 pre[2][2];
#pragma unroll
  for (int i = 0; i < 2; ++i) {
    const float* p = Abase + arow[i] * K_ + aslot[i] * 8;
    pre[i][0] = *(const float4*)p;
    pre[i][1] = *(const float4*)(p + 4);
  }

  for (int kt = 0; kt < 32; ++kt) {
    const int k0 = kt * 32;
#pragma unroll
    for (int i = 0; i < 2; ++i) {
      bf16x8 u;
      u[0] = (__bf16)pre[i][0].x; u[1] = (__bf16)pre[i][0].y;
      u[2] = (__bf16)pre[i][0].z; u[3] = (__bf16)pre[i][0].w;
      u[4] = (__bf16)pre[i][1].x; u[5] = (__bf16)pre[i][1].y;
      u[6] = (__bf16)pre[i][1].z; u[7] = (__bf16)pre[i][1].w;
      *(bf16x8*)(&As[swz(arow[i], aslot[i])]) = u;
    }
#pragma unroll
    for (int j = 0; j < 2; ++j)
      async16(wk + (size_t)(n0 + brow[j]) * K_ + k0 + bs_src[j], &Bs[bs_dst[j]]);
    __syncthreads();
    if (kt + 1 < 32) {
#pragma unroll
      for (int i = 0; i < 2; ++i) {
        const float* p = Abase + arow[i] * K_ + (k0 + 32) + aslot[i] * 8;
        pre[i][0] = *(const float4*)p;
        pre[i][1] = *(const float4*)(p + 4);
      }
    }
    const int g = lane >> 4;
    bf16x8 af[4], bfr[4];
#pragma unroll
    for (int mi = 0; mi < 4; ++mi) {
      int r = wm * 64 + mi * 16 + (lane & 15);
      af[mi] = *(const bf16x8*)(&As[swz(r, g)]);
    }
#pragma unroll
    for (int ni = 0; ni < 4; ++ni) {
      int r = wn * 64 + ni * 16 + (lane & 15);
      bfr[ni] = *(const bf16x8*)(&Bs[swz(r, g)]);
    }
#pragma unroll
    for (int mi = 0; mi < 4; ++mi)
#pragma unroll
      for (int ni = 0; ni < 4; ++ni)
        acc[mi][ni] = __builtin_amdgcn_mfma_f32_16x16x32_bf16(af[mi], bfr[ni], acc[mi][ni], 0, 0, 0);
    __syncthreads();
  }

  const int bb = m0 >> 11;
  float qpv[4], vv[4];
#pragma unroll
  for (int ni = 0; ni < 4; ++ni) {
    int h = n0 + wn * 64 + ni * 16 + (lane & 15);
    qpv[ni] = qp[bb * H_ + h];
    vv[ni]  = v[h];
  }
#pragma unroll
  for (int mi = 0; mi < 4; ++mi) {
    float ps[4] = {0.f, 0.f, 0.f, 0.f};
#pragma unroll
    for (int ni = 0; ni < 4; ++ni)
#pragma unroll
      for (int rr = 0; rr < 4; ++rr)
        ps[rr] += fast_tanh(acc[mi][ni][rr] + qpv[ni]) * vv[ni];
#pragma unroll
    for (int off = 1; off < 16; off <<= 1)
#pragma unroll
      for (int rr = 0; rr < 4; ++rr)
        ps[rr] += __shfl_xor(ps[rr], off, 64);
    if ((lane & 15) == 0) {
      int rowbase = m0 + wm * 64 + mi * 16 + (lane >> 4) * 4;
#pragma unroll
      for (int rr = 0; rr < 4; ++rr)
        atomicAdd(&energy[rowbase + rr], ps[rr]);
    }
  }
}

// ---------------------------------------------------------------- masked softmax
__global__ void softmax_kernel(const float* __restrict__ energy, const void* __restrict__ mask,
                               const int* __restrict__ flag, float* __restrict__ attn) {
  __shared__ float red[256];
  const int b = blockIdx.x, t = threadIdx.x;
  const int fl = flag[0];
  float e[8];
#pragma unroll
  for (int i = 0; i < 8; ++i) {
    int idx = b * S_ + i * 256 + t;
    e[i] = mask_at(mask, fl, idx) ? -INFINITY : energy[idx];
  }
  float mx = e[0];
#pragma unroll
  for (int i = 1; i < 8; ++i) mx = fmaxf(mx, e[i]);
  red[t] = mx; __syncthreads();
  for (int o = 128; o > 0; o >>= 1) { if (t < o) red[t] = fmaxf(red[t], red[t + o]); __syncthreads(); }
  mx = red[0];
  __syncthreads();
  const bool any = (mx > -INFINITY);
  float p[8]; float sum = 0.f;
#pragma unroll
  for (int i = 0; i < 8; ++i) {
    p[i] = (any && e[i] > -INFINITY) ? __expf(e[i] - mx) : 0.f;
    sum += p[i];
  }
  red[t] = sum; __syncthreads();
  for (int o = 128; o > 0; o >>= 1) { if (t < o) red[t] += red[t + o]; __syncthreads(); }
  sum = red[0];
  const float inv = (sum > 0.f) ? 1.f / sum : 0.f;
#pragma unroll
  for (int i = 0; i < 8; ++i) attn[b * S_ + i * 256 + t] = p[i] * inv;
}

// ---------------------------------------------------------------- context, per-(batch,chunk)
__global__ void context_gb(const float* __restrict__ attn, const float* __restrict__ keys,
                           const int* __restrict__ misc, const int* __restrict__ ridx,
                           float* __restrict__ ctx) {
  const int b = blockIdx.y, chunk = blockIdx.x;
  const int jb = misc[144 + 2 * b];
  const int je = misc[144 + 2 * b + 2];     // sentinel at [144+128] covers b=63
  const int j0 = jb + chunk * 64;
  if (j0 >= je) return;
  const int j1 = (j0 + 64 < je) ? j0 + 64 : je;
  const int t = threadIdx.x;                 // k = 4t..4t+3
  float4 acc = {0.f, 0.f, 0.f, 0.f};
#pragma unroll 4
  for (int j = j0; j < j1; ++j) {
    const int row = ridx[j];
    const float a = attn[row];
    float4 kv = *(const float4*)(keys + (size_t)row * K_ + t * 4);
    acc.x += a * kv.x; acc.y += a * kv.y; acc.z += a * kv.z; acc.w += a * kv.w;
  }
  float* cb = ctx + b * K_ + t * 4;
  atomicAdd(cb + 0, acc.x); atomicAdd(cb + 1, acc.y);
  atomicAdd(cb + 2, acc.z); atomicAdd(cb + 3, acc.w);
}

// ---------------------------------------------------------------- fallback context (dense f32)
__global__ void context_kernel(const float* __restrict__ attn, const float* __restrict__ keys,
                               float* __restrict__ ctx) {
  const int b = blockIdx.y;
  const int sc = blockIdx.x;
  const int t = threadIdx.x;
  const float* kb = keys + ((size_t)b * S_ + sc * 128) * K_;
  const float* ab = attn + b * S_ + sc * 128;
  float4 acc = {0.f, 0.f, 0.f, 0.f};
  for (int s = 0; s < 128; ++s) {
    float a = ab[s];
    if (a != 0.f) {
      float4 kv = *(const float4*)(kb + (size_t)s * K_ + t * 4);
      acc.x += a * kv.x; acc.y += a * kv.y; acc.z += a * kv.z; acc.w += a * kv.w;
    }
  }
  float* cb = ctx + b * K_ + t * 4;
  atomicAdd(cb + 0, acc.x);
  atomicAdd(cb + 1, acc.y);
  atomicAdd(cb + 2, acc.z);
  atomicAdd(cb + 3, acc.w);
}

// ---------------------------------------------------------------- launch
extern "C" void kernel_launch(void* const* d_in, const int* in_sizes, int n_in,
                              void* d_out, int out_size, void* d_ws, size_t ws_size,
                              hipStream_t stream) {
  (void)in_sizes; (void)n_in; (void)out_size;
  const float* query = (const float*)d_in[0];
  const float* keys  = (const float*)d_in[1];
  const void*  mask  = d_in[2];
  const float* Wq    = (const float*)d_in[3];
  const float* Wk    = (const float*)d_in[4];
  const float* v     = (const float*)d_in[5];

  float* ctx  = (float*)d_out;             // [64][1024]
  float* attn = (float*)d_out + B_ * K_;   // [64][2048]

  char* ws = (char*)d_ws;
  float*          energy = (float*)ws;                              // 512 KiB
  float*          qp     = (float*)(ws + (512 << 10));              // 256 KiB
  unsigned short* wkb    = (unsigned short*)(ws + (768 << 10));     // 2 MiB
  int*            misc   = (int*)(ws + (768 << 10) + (2 << 20));    // 4 KiB
  int*            ridx   = (int*)(ws + (3 << 20));                  // 512 KiB

  const bool big = ws_size >= (size_t)(4 << 20);

  hipMemsetAsync(energy, 0, (size_t)M_ * 4, stream);
  hipMemsetAsync(ctx, 0, (size_t)B_ * K_ * 4, stream);
  detect_mask<<<1, 256, 0, stream>>>((const unsigned int*)mask, misc);
  convert_wk<<<(H_ * K_ / 4) / 256, 256, 0, stream>>>(Wk, wkb);
  qp_kernel<<<dim3(4, B_), 256, 0, stream>>>(query, Wq, qp);
  if (big) {
    mask_count<<<128, 256, 0, stream>>>(mask, misc);
    mask_scan<<<1, 64, 0, stream>>>(misc);
    mask_writeidx<<<128, 256, 0, stream>>>(mask, misc, ridx);
    gemm_energy_g<<<(M_ / 128) * (H_ / 128), 256, 0, stream>>>(
        keys, (const __bf16*)wkb, qp, v, energy, misc, ridx);
    softmax_kernel<<<B_, 256, 0, stream>>>(energy, mask, misc, attn);
    context_gb<<<dim3(32, B_), 256, 0, stream>>>(attn, keys, misc, ridx, ctx);
  } else {
    gemm_energy<<<(M_ / 128) * (H_ / 128), 256, 0, stream>>>(
        keys, (const __bf16*)wkb, qp, v, energy);
    softmax_kernel<<<B_, 256, 0, stream>>>(energy, mask, misc, attn);
    context_kernel<<<dim3(S_ / 128, B_), 256, 0, stream>>>(attn, keys, ctx);
  }
}